// Round 7
// baseline (564.141 us; speedup 1.0000x reference)
//
#include <hip/hip_runtime.h>
#include <math.h>

// MMD, Gaussian kernel, bandwidth=512. X:[8192,512] Y:[8192,512] fp32.
// S_AB = sum_ij exp(-||a_i-b_j||^2/512); final combine emulates the
// reference's fp32 logsumexp->exp->combine path (see finalize_kernel).
//
// GEMM on bf16 MFMA via split-bf16 3-product (hi*hi' + hi*lo' + lo*hi').
// Round-7: barrier-free K-loop. Each wave stages its OWN B tile into a
// private LDS double-buffer via global_load_lds (no VGPR cost) and
// prefetches its A frags into registers (32 VGPR). No __syncthreads in
// the K-loop: the only stall is the wave's own vmcnt(0) for DMAs issued
// one full MFMA-window earlier (R4/R5 plateaued at 45% MfmaUtil on the
// collective barrier drain; R6's all-register variant spilled and hit
// the L3 bandwidth wall). Global layout [ks][pgroup32][khalf][p%32]
// makes DMA and ds_read lane-linear (conflict-free).
// Per-element accumulation order unchanged -> d2 bits identical.

#define D      512
#define BTM    128
#define BTN    256
#define BK     16
#define KSTEPS (D / BK)

typedef __attribute__((ext_vector_type(8)))  short  short8;   // 8 bf16
typedef __attribute__((ext_vector_type(16))) float  f32x16;   // 32x32 acc

__device__ __forceinline__ unsigned short bf16_rne(float x) {
    unsigned u = __float_as_uint(x);
    return (unsigned short)((u + 0x7fffu + ((u >> 16) & 1u)) >> 16);
}
__device__ __forceinline__ float bf16_f32(unsigned short b) {
    return __uint_as_float(((unsigned)b) << 16);
}
__device__ __forceinline__ void split8(const float v[8], uint4& hi, uint4& lo) {
    unsigned h[8], l[8];
    #pragma unroll
    for (int j = 0; j < 8; j++) {
        unsigned short bh = bf16_rne(v[j]);
        float r = v[j] - bf16_f32(bh);          // exact (Sterbenz)
        unsigned short bl = bf16_rne(r);
        h[j] = bh; l[j] = bl;
    }
    hi.x = h[0] | (h[1] << 16); hi.y = h[2] | (h[3] << 16);
    hi.z = h[4] | (h[5] << 16); hi.w = h[6] | (h[7] << 16);
    lo.x = l[0] | (l[1] << 16); lo.y = l[2] | (l[3] << 16);
    lo.z = l[4] | (l[5] << 16); lo.w = l[6] | (l[7] << 16);
}

// async global->LDS, 16B per lane; dest = wave-uniform base + lane*16
__device__ __forceinline__ void lds16(const uint4* g, uint4* l) {
    __builtin_amdgcn_global_load_lds(
        (const __attribute__((address_space(1))) void*)g,
        (__attribute__((address_space(3))) void*)(unsigned int)(uintptr_t)(void*)l,
        16, 0, 0);
}

// one-time split: src[npts][512] fp32 -> hi/lo, unit layout
// [kstep][p>>5][khalf][p&31] (16B units) => frag reads are lane-linear
__global__ __launch_bounds__(256)
void convert_kernel(const float* __restrict__ src, uint4* __restrict__ hi,
                    uint4* __restrict__ lo, int npts) {
    const int ks = blockIdx.y;
    const int p  = blockIdx.x * 256 + threadIdx.x;
    if (p >= npts) return;
    const float* s = src + (size_t)p * D + ks * BK;
    float v[16];
    *(float4*)&v[0]  = *(const float4*)(s);
    *(float4*)&v[4]  = *(const float4*)(s + 4);
    *(float4*)&v[8]  = *(const float4*)(s + 8);
    *(float4*)&v[12] = *(const float4*)(s + 12);
    uint4 h0, l0, h1, l1;
    split8(&v[0], h0, l0);                      // khalf 0 (k 0..7)
    split8(&v[8], h1, l1);                      // khalf 1 (k 8..15)
    size_t u = (size_t)ks * npts * 2 + (size_t)(p >> 5) * 64 + (p & 31);
    hi[u] = h0; hi[u + 32] = h1;
    lo[u] = l0; lo[u + 32] = l1;
}

__global__ __launch_bounds__(256)
void row_norms_kernel(const float* __restrict__ X, const float* __restrict__ Y,
                      float* __restrict__ X2, float* __restrict__ Y2, int N, int M) {
    const int wave = threadIdx.x >> 6;
    const int lane = threadIdx.x & 63;
    const int row  = blockIdx.x * 4 + wave;
    const float* src; float* dst; int r;
    if (row < N)          { src = X; dst = X2; r = row; }
    else if (row < N + M) { src = Y; dst = Y2; r = row - N; }
    else return;
    const float* p = src + (size_t)r * D;
    float s = 0.f;
    #pragma unroll
    for (int c = 0; c < D; c += 64) {
        float v = p[c + lane];
        s = fmaf(v, v, s);
    }
    #pragma unroll
    for (int off = 32; off > 0; off >>= 1) s += __shfl_down(s, off);
    if (lane == 0) dst[r] = s;
}

// order-preserving float<->uint key (for atomicMin over f32)
__device__ inline unsigned float_key(float f) {
    unsigned u = __float_as_uint(f);
    return (u & 0x80000000u) ? ~u : (u | 0x80000000u);
}
__device__ inline float key_float(unsigned k) {
    return __uint_as_float((k & 0x80000000u) ? (k ^ 0x80000000u) : ~k);
}

struct AF { short8 h[2], l[2]; };               // A frags for one K-step

// grid (64,32,3): z=0 XX (sym), z=1 XY, z=2 YY (sym)
__global__ __launch_bounds__(256, 2)
void pair_exp_sum_kernel(const uint4* __restrict__ Xhi, const uint4* __restrict__ Xlo,
                         const uint4* __restrict__ Yhi, const uint4* __restrict__ Ylo,
                         const float* __restrict__ X2, const float* __restrict__ Y2,
                         double* __restrict__ accum, unsigned* __restrict__ minkey,
                         int N, int M) {
    const int z = blockIdx.z;
    const uint4 *Ahi, *Alo, *Bhi, *Blo; const float *An, *Bn; bool sym; int na, nb;
    if (z == 0)      { Ahi=Xhi; Alo=Xlo; Bhi=Xhi; Blo=Xlo; An=X2; Bn=X2; sym=true;  na=N; nb=N; }
    else if (z == 1) { Ahi=Xhi; Alo=Xlo; Bhi=Yhi; Blo=Ylo; An=X2; Bn=Y2; sym=false; na=N; nb=M; }
    else             { Ahi=Yhi; Alo=Ylo; Bhi=Yhi; Blo=Ylo; An=Y2; Bn=Y2; sym=true;  na=M; nb=M; }
    const int bi = blockIdx.x, bj = blockIdx.y;
    if (sym && (2 * bj + 1) < bi) return;       // both 128-col halves below diag

    __shared__ uint4  sB[4][2][512];            // per-wave private: 2 bufs x 8 KB
    __shared__ float  smN[BTM + BTN];
    __shared__ double wsum[4];
    __shared__ float  wmin[4];

    const int tid  = threadIdx.x;
    const int wave = tid >> 6, lane = tid & 63;
    const int wy = wave >> 1, wx = wave & 1;    // 2x2 waves, each 64x128
    const int row0 = bi * BTM, col0 = bj * BTN;

    if (tid < BTM) smN[tid] = An[row0 + tid];
    smN[BTM + tid] = Bn[col0 + tid];
    __syncthreads();                            // last block-wide sync til epilogue

    const size_t strideA = (size_t)na * 2;      // 16B units per kstep
    const size_t strideB = (size_t)nb * 2;

    // A frag source (short8 units): base + g*64 + lane, g=0,1
    const short8* pAhi = (const short8*)Ahi + (size_t)row0 * 2 + 128 * wy + lane;
    const short8* pAlo = (const short8*)Alo + (size_t)row0 * 2 + 128 * wy + lane;
    // B stage source (uint4 units): contiguous 256 units hi + 256 lo
    const uint4* gBhi = Bhi + (size_t)col0 * 2 + 256 * wx + lane;
    const uint4* gBlo = Blo + (size_t)col0 * 2 + 256 * wx + lane;

    uint4* sm0 = &sB[wave][0][0];
    uint4* sm1 = &sB[wave][1][0];

    f32x16 acc[2][4];
    #pragma unroll
    for (int g = 0; g < 2; g++)
        #pragma unroll
        for (int c = 0; c < 4; c++)
            #pragma unroll
            for (int i = 0; i < 16; i++) acc[g][c][i] = 0.f;

    auto stage = [&](int ks, uint4* sm) {       // 8 KB via 8 async DMAs
        const uint4* sh = gBhi + (size_t)ks * strideB;
        const uint4* sl = gBlo + (size_t)ks * strideB;
        #pragma unroll
        for (int t = 0; t < 4; t++) lds16(sh + t * 64, sm + t * 64 + lane);
        #pragma unroll
        for (int t = 0; t < 4; t++) lds16(sl + t * 64, sm + 256 + t * 64 + lane);
    };
    auto loadA = [&](int ks, AF& f) {           // 4 KB direct to VGPR
        const short8* ph = pAhi + (size_t)ks * strideA;
        const short8* pl = pAlo + (size_t)ks * strideA;
        f.h[0] = ph[0]; f.h[1] = ph[64];
        f.l[0] = pl[0]; f.l[1] = pl[64];
    };
    auto readB = [&](const uint4* sm, short8* bh, short8* bl) {
        const short8* pB = (const short8*)sm;   // lane-linear: conflict-free
        #pragma unroll
        for (int c = 0; c < 4; c++) { bh[c] = pB[c * 64 + lane]; bl[c] = pB[256 + c * 64 + lane]; }
    };
    auto domfma = [&](const AF& a, const short8* bh, const short8* bl) {
        // same per-element order as rounds 3-6: all hh, all hl, all lh
        #pragma unroll
        for (int g = 0; g < 2; g++)
            #pragma unroll
            for (int c = 0; c < 4; c++)
                acc[g][c] = __builtin_amdgcn_mfma_f32_32x32x16_bf16(a.h[g], bh[c], acc[g][c], 0, 0, 0);
        #pragma unroll
        for (int g = 0; g < 2; g++)
            #pragma unroll
            for (int c = 0; c < 4; c++)
                acc[g][c] = __builtin_amdgcn_mfma_f32_32x32x16_bf16(a.h[g], bl[c], acc[g][c], 0, 0, 0);
        #pragma unroll
        for (int g = 0; g < 2; g++)
            #pragma unroll
            for (int c = 0; c < 4; c++)
                acc[g][c] = __builtin_amdgcn_mfma_f32_32x32x16_bf16(a.l[g], bh[c], acc[g][c], 0, 0, 0);
    };

    AF A0, A1;
    stage(0, sm0);
    loadA(0, A0);

    for (int ks = 0; ks < KSTEPS; ks += 2) {
        short8 bh[4], bl[4];
        // ---- even step: consume buf0/A0, stage ks+1 into buf1/A1 ----
        __builtin_amdgcn_s_waitcnt(0x0F70);     // vmcnt(0): this wave's step-ks ops
        readB(sm0, bh, bl);
        __builtin_amdgcn_sched_barrier(0);      // keep DMA-issue below ds_reads
        stage(ks + 1, sm1);                     // ks+1 <= 31 always
        loadA(ks + 1, A1);
        __builtin_amdgcn_sched_barrier(0);      // issue DMAs before MFMA block
        domfma(A0, bh, bl);
        // ---- odd step: consume buf1/A1, stage ks+2 into buf0/A0 ----
        __builtin_amdgcn_s_waitcnt(0x0F70);
        readB(sm1, bh, bl);
        __builtin_amdgcn_sched_barrier(0);
        if (ks + 2 < KSTEPS) { stage(ks + 2, sm0); loadA(ks + 2, A0); }
        __builtin_amdgcn_sched_barrier(0);
        domfma(A1, bh, bl);
    }

    // per-wave triangular weight (col-128-half granularity)
    float wgt = 1.f;
    if (sym) {
        int cblk = 2 * bj + wx;
        wgt = (cblk > bi) ? 2.f : (cblk == bi ? 1.f : 0.f);
    }

    // epilogue: d2 = |a|^2+|b|^2-2ab; min d2; sum exp(-d2/512)
    // C/D layout (m74/m101): col=lane&31, row=(reg&3)+8*(reg>>2)+4*(lane>>5)
    const int fp = lane & 31, fh = lane >> 5;
    double s = 0.0;
    float dmin = 1e30f;
    if (wgt != 0.f) {
        const float* rowN = &smN[64 * wy];
        const float* colN = &smN[BTM + 128 * wx];
        #pragma unroll
        for (int g = 0; g < 2; g++)
            #pragma unroll
            for (int c = 0; c < 4; c++) {
                float cn = colN[32 * c + fp];
                float rs = 0.f;
                #pragma unroll
                for (int r = 0; r < 16; r++) {
                    int r32 = (r & 3) + 8 * (r >> 2) + 4 * fh;
                    float d2 = rowN[32 * g + r32] + cn - 2.0f * acc[g][c][r];
                    dmin = fminf(dmin, d2);
                    rs += expf(d2 * (-1.0f / 512.0f));
                }
                s += (double)rs;
            }
        s *= (double)wgt;
    }

    #pragma unroll
    for (int off = 32; off > 0; off >>= 1) {
        s += __shfl_down(s, off);
        dmin = fminf(dmin, __shfl_down(dmin, off));
    }
    if (lane == 0) { wsum[wave] = s; wmin[wave] = dmin; }
    __syncthreads();
    if (tid == 0) {
        double tot = wsum[0] + wsum[1] + wsum[2] + wsum[3];
        atomicAdd(&accum[z], tot);
        float bm = fminf(fminf(wmin[0], wmin[1]), fminf(wmin[2], wmin[3]));
        atomicMin(&minkey[z], float_key(bm));
    }
}

__global__ void finalize_kernel(const double* __restrict__ accum,
                                const unsigned* __restrict__ minkey,
                                float* __restrict__ out, int N, int M) {
    if (threadIdx.x == 0 && blockIdx.x == 0) {
        float Sp[3];
        #pragma unroll
        for (int z = 0; z < 3; z++) {
            float m = key_float(minkey[z]) * (-1.0f / 512.0f);
            double Sshift = accum[z] * exp(-(double)m);
            float r = (float)log(Sshift);       // correctly-rounded f32 log
            float lse = r + m;                  // fp32 add, as jax
            Sp[z] = (float)exp((double)lse);    // correctly-rounded f32 exp
        }
        float nf  = (float)N, mf = (float)M;
        float nn1 = (float)((double)N * (double)(N - 1));
        float mm1 = (float)((double)M * (double)(M - 1));
        float nm  = (float)((double)N * (double)M);
        float xx = (Sp[0] - nf) / nn1;
        float xy =  Sp[1]       / nm;
        float yy = (Sp[2] - mf) / mm1;
        out[0] = xx - 2.0f * xy + yy;
    }
}

extern "C" void kernel_launch(void* const* d_in, const int* in_sizes, int n_in,
                              void* d_out, int out_size, void* d_ws, size_t ws_size,
                              hipStream_t stream) {
    const float* X = (const float*)d_in[0];
    const float* Y = (const float*)d_in[1];
    const int N = in_sizes[0] / D;
    const int M = in_sizes[1] / D;

    // ws: accum(3 f64)@0; minkey(3 u32)@32; X2@64; Y2; then 256B-aligned
    // swizzled bf16 arrays Xhi,Xlo,Yhi,Ylo (N*D*2 B each; 32 MB total)
    double*   accum  = (double*)d_ws;
    unsigned* minkey = (unsigned*)((char*)d_ws + 32);
    float*    X2     = (float*)((char*)d_ws + 64);
    float*    Y2     = X2 + N;
    size_t off = (64 + (size_t)(N + M) * 4 + 255) & ~(size_t)255;
    size_t asz = (size_t)N * D * 2;             // bytes per array (N==M)
    uint4* Xhi = (uint4*)((char*)d_ws + off);
    uint4* Xlo = (uint4*)((char*)d_ws + off + asz);
    uint4* Yhi = (uint4*)((char*)d_ws + off + 2 * asz);
    uint4* Ylo = (uint4*)((char*)d_ws + off + 3 * asz);

    hipMemsetAsync(accum, 0, 32, stream);
    hipMemsetAsync(minkey, 0xFF, 32, stream);

    row_norms_kernel<<<(N + M + 3) / 4, 256, 0, stream>>>(X, Y, X2, Y2, N, M);
    convert_kernel<<<dim3((N + 255) / 256, KSTEPS), 256, 0, stream>>>(X, Xhi, Xlo, N);
    convert_kernel<<<dim3((M + 255) / 256, KSTEPS), 256, 0, stream>>>(Y, Yhi, Ylo, M);

    dim3 grid(N / BTM, M / BTN, 3);
    pair_exp_sum_kernel<<<grid, 256, 0, stream>>>(Xhi, Xlo, Yhi, Ylo, X2, Y2,
                                                  accum, minkey, N, M);

    finalize_kernel<<<1, 64, 0, stream>>>(accum, minkey, (float*)d_out, N, M);
}

// Round 9
// 429.371 us; speedup vs baseline: 1.3139x; 1.3139x over previous
//
#include <hip/hip_runtime.h>
#include <math.h>

// MMD, Gaussian kernel, bandwidth=512. X:[8192,512] Y:[8192,512] fp32.
// S_AB = sum_ij exp(-||a_i-b_j||^2/512); final combine emulates the
// reference's fp32 logsumexp->exp->combine path (see finalize_kernel).
//
// Round-9 architecture (from R8's one-lse-cell failure analysis):
//  * lse = fl(fl(log S - m) + m) behaves as round(x - m): the output cell
//    shifts with m at SUB-ULP granularity. m must therefore be the exact
//    bits that won rounds 3-7 (the bf16-split 3-product d2 field's min),
//    not merely "fp32-accurate".
//  * S only needs accuracy << 1 cell (17 units of 9.1e6): the fp16
//    single-product GEMM (3x less MFMA) shifts S by ~0.02 units. Fine.
//  * So: fast fp16 S-pass for the sums + tiny refine kernels that
//    recompute the R5 bf16-split d2 BIT-EXACTLY (same split8 values,
//    same per-element MFMA order hh,hl,lh per BK=16 step, same 32x32x16
//    shape, same epilogue expression) on only the candidate-min blocks:
//    XX/YY diag-touching blocks (off-diag d2 >= ~650), XY blocks within
//    0.5 of the global fp16 min (fp16 noise sigma ~1e-2).

#define D      512
#define BTM    128
#define BTN    256
#define BK     16
#define KSTEPS (D / BK)

// 16B-unit offsets in the refine kernel's LDS (R5 layout [point*2+khalf])
#define AHI 0
#define ALO 256
#define BHI 512
#define BLO 1024

typedef _Float16 half8 __attribute__((ext_vector_type(8)));
typedef __attribute__((ext_vector_type(8)))  short  short8;   // 8 bf16
typedef __attribute__((ext_vector_type(16))) float  f32x16;   // 32x32 acc

union U4H8 { uint4 u; half8 h; };

__device__ __forceinline__ unsigned short bf16_rne(float x) {
    unsigned u = __float_as_uint(x);
    return (unsigned short)((u + 0x7fffu + ((u >> 16) & 1u)) >> 16);
}
__device__ __forceinline__ float bf16_f32(unsigned short b) {
    return __uint_as_float(((unsigned)b) << 16);
}
__device__ __forceinline__ void split8(const float v[8], uint4& hi, uint4& lo) {
    unsigned h[8], l[8];
    #pragma unroll
    for (int j = 0; j < 8; j++) {
        unsigned short bh = bf16_rne(v[j]);
        float r = v[j] - bf16_f32(bh);          // exact (Sterbenz)
        unsigned short bl = bf16_rne(r);
        h[j] = bh; l[j] = bl;
    }
    hi.x = h[0] | (h[1] << 16); hi.y = h[2] | (h[3] << 16);
    hi.z = h[4] | (h[5] << 16); hi.w = h[6] | (h[7] << 16);
    lo.x = l[0] | (l[1] << 16); lo.y = l[2] | (l[3] << 16);
    lo.z = l[4] | (l[5] << 16); lo.w = l[6] | (l[7] << 16);
}

// async global->LDS, 16B per lane
__device__ __forceinline__ void lds16(const uint4* g, uint4* l) {
    __builtin_amdgcn_global_load_lds(
        (const __attribute__((address_space(1))) void*)g,
        (__attribute__((address_space(3))) void*)(unsigned int)(uintptr_t)(void*)l,
        16, 0, 0);
}

// fp16 convert: src[npts][512] fp32 -> [kstep][p>>5][khalf][p&31] 16B units
__global__ __launch_bounds__(256)
void convert_h_kernel(const float* __restrict__ src, uint4* __restrict__ dst, int npts) {
    const int ks = blockIdx.y;
    const int p  = blockIdx.x * 256 + threadIdx.x;
    if (p >= npts) return;
    const float* s = src + (size_t)p * D + ks * BK;
    float v[16];
    *(float4*)&v[0]  = *(const float4*)(s);
    *(float4*)&v[4]  = *(const float4*)(s + 4);
    *(float4*)&v[8]  = *(const float4*)(s + 8);
    *(float4*)&v[12] = *(const float4*)(s + 12);
    U4H8 a, b;
    #pragma unroll
    for (int j = 0; j < 8; j++) { a.h[j] = (_Float16)v[j]; b.h[j] = (_Float16)v[8 + j]; }
    size_t u = (size_t)ks * npts * 2 + (size_t)(p >> 5) * 64 + (p & 31);
    dst[u] = a.u; dst[u + 32] = b.u;
}

__global__ __launch_bounds__(256)
void row_norms_kernel(const float* __restrict__ X, const float* __restrict__ Y,
                      float* __restrict__ X2, float* __restrict__ Y2, int N, int M) {
    const int wave = threadIdx.x >> 6;
    const int lane = threadIdx.x & 63;
    const int row  = blockIdx.x * 4 + wave;
    const float* src; float* dst; int r;
    if (row < N)          { src = X; dst = X2; r = row; }
    else if (row < N + M) { src = Y; dst = Y2; r = row - N; }
    else return;
    const float* p = src + (size_t)r * D;
    float s = 0.f;
    #pragma unroll
    for (int c = 0; c < D; c += 64) {
        float v = p[c + lane];
        s = fmaf(v, v, s);
    }
    #pragma unroll
    for (int off = 32; off > 0; off >>= 1) s += __shfl_down(s, off);
    if (lane == 0) dst[r] = s;
}

__device__ inline unsigned float_key(float f) {
    unsigned u = __float_as_uint(f);
    return (u & 0x80000000u) ? ~u : (u | 0x80000000u);
}
__device__ inline float key_float(unsigned k) {
    return __uint_as_float((k & 0x80000000u) ? (k ^ 0x80000000u) : ~k);
}

// ---------- fp16 S-pass: grid (64,32,3): z=0 XX (sym), 1 XY, 2 YY ----------
__global__ __launch_bounds__(256, 2)
void pair_exp_sum_kernel(const uint4* __restrict__ Xh, const uint4* __restrict__ Yh,
                         const float* __restrict__ X2, const float* __restrict__ Y2,
                         double* __restrict__ accum, float* __restrict__ bmin,
                         int N, int M) {
    const int z = blockIdx.z;
    const uint4 *Ah, *Bh; const float *An, *Bn; bool sym; int na, nb;
    if (z == 0)      { Ah = Xh; Bh = Xh; An = X2; Bn = X2; sym = true;  na = N; nb = N; }
    else if (z == 1) { Ah = Xh; Bh = Yh; An = X2; Bn = Y2; sym = false; na = N; nb = M; }
    else             { Ah = Yh; Bh = Yh; An = Y2; Bn = Y2; sym = true;  na = M; nb = M; }
    const int bi = blockIdx.x, bj = blockIdx.y;
    if (sym && (2 * bj + 1) < bi) return;        // both 128-col halves below diag

    __shared__ uint4  smem[2][768];              // [buf][A:0-255|B:256-767], 2x12 KB
    __shared__ float  smN[BTM + BTN];
    __shared__ double wsum[4];
    __shared__ float  wmin[4];

    const int tid  = threadIdx.x;
    const int wave = tid >> 6, lane = tid & 63;
    const int wy = wave >> 1, wx = wave & 1;     // 2x2 waves, each 64x128
    const int row0 = bi * BTM, col0 = bj * BTN;

    if (tid < BTM) smN[tid] = An[row0 + tid];
    smN[BTM + tid] = Bn[col0 + tid];

    const int wl = wave * 64 + lane;
    const size_t strideA = (size_t)na * 2;       // 16B units per kstep
    const size_t strideB = (size_t)nb * 2;
    const uint4* gA  = Ah + (size_t)(row0 >> 5) * 64 + wl;
    const uint4* gB0 = Bh + (size_t)(col0 >> 5) * 64 + wl;
    const uint4* gB1 = gB0 + 256;

    f32x16 acc[2][4];
    #pragma unroll
    for (int g = 0; g < 2; g++)
        #pragma unroll
        for (int c = 0; c < 4; c++)
            #pragma unroll
            for (int i = 0; i < 16; i++) acc[g][c][i] = 0.f;

    auto stage = [&](int buf, int ks) {          // 12 KB via 3 DMAs/thread
        lds16(gA  + (size_t)ks * strideA, &smem[buf][wl]);
        lds16(gB0 + (size_t)ks * strideB, &smem[buf][256 + wl]);
        lds16(gB1 + (size_t)ks * strideB, &smem[buf][512 + wl]);
    };
    auto compute = [&](int buf) {
        const half8* p = (const half8*)&smem[buf][0];
        half8 ah[2], bh[4];
        #pragma unroll
        for (int g = 0; g < 2; g++) ah[g] = p[(2 * wy + g) * 64 + lane];
        #pragma unroll
        for (int c = 0; c < 4; c++) bh[c] = p[256 + (4 * wx + c) * 64 + lane];
        #pragma unroll
        for (int g = 0; g < 2; g++)
            #pragma unroll
            for (int c = 0; c < 4; c++)
                acc[g][c] = __builtin_amdgcn_mfma_f32_32x32x16_f16(ah[g], bh[c], acc[g][c], 0, 0, 0);
    };

    stage(0, 0);
    __syncthreads();

    int pb = 0;
    for (int ks = 1; ks < KSTEPS; ks++) {
        stage(pb ^ 1, ks);
        compute(pb);
        __syncthreads();
        pb ^= 1;
    }
    compute(pb);

    float wgt = 1.f;
    if (sym) {
        int cblk = 2 * bj + wx;
        wgt = (cblk > bi) ? 2.f : (cblk == bi ? 1.f : 0.f);
    }

    // C/D layout (m74/m101): col=lane&31, row=(reg&3)+8*(reg>>2)+4*(lane>>5)
    const int fp = lane & 31, fh = lane >> 5;
    double s = 0.0;
    float dmin = 1e30f;
    if (wgt != 0.f) {
        const float* rowN = &smN[64 * wy];
        const float* colN = &smN[BTM + 128 * wx];
        #pragma unroll
        for (int g = 0; g < 2; g++)
            #pragma unroll
            for (int c = 0; c < 4; c++) {
                float cn = colN[32 * c + fp];
                float rs = 0.f;
                #pragma unroll
                for (int r = 0; r < 16; r++) {
                    int r32 = (r & 3) + 8 * (r >> 2) + 4 * fh;
                    float d2 = rowN[32 * g + r32] + cn - 2.0f * acc[g][c][r];
                    dmin = fminf(dmin, d2);
                    rs += expf(d2 * (-1.0f / 512.0f));
                }
                s += (double)rs;
            }
        s *= (double)wgt;
    }

    #pragma unroll
    for (int off = 32; off > 0; off >>= 1) {
        s += __shfl_down(s, off);
        dmin = fminf(dmin, __shfl_down(dmin, off));
    }
    if (lane == 0) { wsum[wave] = s; wmin[wave] = dmin; }
    __syncthreads();
    if (tid == 0) {
        atomicAdd(&accum[z], wsum[0] + wsum[1] + wsum[2] + wsum[3]);
        if (z == 1)                              // noisy (+-~0.02) block min
            bmin[bi * gridDim.y + bj] = fminf(fminf(wmin[0], wmin[1]),
                                              fminf(wmin[2], wmin[3]));
    }
}

__global__ __launch_bounds__(256)
void xy_gmin_kernel(const float* __restrict__ bmin, float* __restrict__ gmin, int nblk) {
    float m = 1e30f;
    for (int i = threadIdx.x; i < nblk; i += 256) m = fminf(m, bmin[i]);
    #pragma unroll
    for (int off = 32; off > 0; off >>= 1) m = fminf(m, __shfl_down(m, off));
    __shared__ float wm[4];
    if ((threadIdx.x & 63) == 0) wm[threadIdx.x >> 6] = m;
    __syncthreads();
    if (threadIdx.x == 0) gmin[0] = fminf(fminf(wm[0], wm[1]), fminf(wm[2], wm[3]));
}

// ---------- refine: R5-bit-exact bf16-split 3-product d2 min --------------
// diagmode=1: grid(64,1), bj=bi>>1 (XX/YY diag-touching blocks).
// diagmode=0: grid(64,32), XY blocks within 0.5 of global fp16 min.
// Reproduces rounds 3-7's m bitwise: same split8 values, same per-element
// MFMA order (all hh, all hl, all lh per BK=16 step), same 32x32x16 shape,
// same epilogue expression text as the R3-R7 kernels.
__global__ __launch_bounds__(256)
void refine_min_kernel(const float* __restrict__ A, const float* __restrict__ B,
                       const float* __restrict__ An, const float* __restrict__ Bn,
                       const float* __restrict__ bmin, const float* __restrict__ gmin,
                       unsigned* __restrict__ minkey, int zidx, int diagmode) {
    const int bi = blockIdx.x;
    int bj;
    if (diagmode) bj = bi >> 1;
    else {
        bj = blockIdx.y;
        if (!(bmin[bi * gridDim.y + bj] < gmin[0] + 0.5f)) return;
    }
    const int row0 = bi * BTM, col0 = bj * BTN;

    __shared__ uint4 smem[1536];                 // Ahi|Alo|Bhi|Blo (R5 layout)
    __shared__ float smN[BTM + BTN];
    __shared__ float wmin[4];

    const int tid  = threadIdx.x;
    const int wave = tid >> 6, lane = tid & 63;
    const int wy = wave >> 1, wx = wave & 1;
    if (tid < BTM) smN[tid] = An[row0 + tid];
    smN[BTM + tid] = Bn[col0 + tid];

    const int fp = lane & 31, fh = lane >> 5;
    int au[2], bu[4];
    #pragma unroll
    for (int g = 0; g < 2; g++) au[g] = (64 * wy + 32 * g + fp) * 2 + fh;
    #pragma unroll
    for (int c = 0; c < 4; c++) bu[c] = (128 * wx + 32 * c + fp) * 2 + fh;

    f32x16 acc[2][4];
    #pragma unroll
    for (int g = 0; g < 2; g++)
        #pragma unroll
        for (int c = 0; c < 4; c++)
            #pragma unroll
            for (int i = 0; i < 16; i++) acc[g][c][i] = 0.f;

    for (int ks = 0; ks < KSTEPS; ks++) {
        __syncthreads();                         // prev-step LDS reads done
        {   // A: unit tid (point tid>>1, khalf tid&1)
            const float* s = A + (size_t)(row0 + (tid >> 1)) * D + ks * BK + (tid & 1) * 8;
            float v[8];
            *(float4*)&v[0] = *(const float4*)s;
            *(float4*)&v[4] = *(const float4*)(s + 4);
            uint4 hi, lo; split8(v, hi, lo);
            smem[AHI + tid] = hi; smem[ALO + tid] = lo;
        }
        #pragma unroll
        for (int t = 0; t < 2; t++) {            // B: units tid, tid+256
            int u = tid + t * 256;
            const float* s = B + (size_t)(col0 + (u >> 1)) * D + ks * BK + (u & 1) * 8;
            float v[8];
            *(float4*)&v[0] = *(const float4*)s;
            *(float4*)&v[4] = *(const float4*)(s + 4);
            uint4 hi, lo; split8(v, hi, lo);
            smem[BHI + u] = hi; smem[BLO + u] = lo;
        }
        __syncthreads();
        {   // R5 compute, verbatim order: all hh, all hl, all lh
            const short8* p = (const short8*)&smem[0];
            short8 ah[2], al[2], bh[4], bl[4];
            #pragma unroll
            for (int g = 0; g < 2; g++) { ah[g] = p[AHI + au[g]]; al[g] = p[ALO + au[g]]; }
            #pragma unroll
            for (int c = 0; c < 4; c++) { bh[c] = p[BHI + bu[c]]; bl[c] = p[BLO + bu[c]]; }
            #pragma unroll
            for (int g = 0; g < 2; g++)
                #pragma unroll
                for (int c = 0; c < 4; c++)
                    acc[g][c] = __builtin_amdgcn_mfma_f32_32x32x16_bf16(ah[g], bh[c], acc[g][c], 0, 0, 0);
            #pragma unroll
            for (int g = 0; g < 2; g++)
                #pragma unroll
                for (int c = 0; c < 4; c++)
                    acc[g][c] = __builtin_amdgcn_mfma_f32_32x32x16_bf16(ah[g], bl[c], acc[g][c], 0, 0, 0);
            #pragma unroll
            for (int g = 0; g < 2; g++)
                #pragma unroll
                for (int c = 0; c < 4; c++)
                    acc[g][c] = __builtin_amdgcn_mfma_f32_32x32x16_bf16(al[g], bh[c], acc[g][c], 0, 0, 0);
        }
    }

    // epilogue: min d2 only, same expression text as R5
    float dmin = 1e30f;
    const float* rowN = &smN[64 * wy];
    const float* colN = &smN[BTM + 128 * wx];
    #pragma unroll
    for (int g = 0; g < 2; g++)
        #pragma unroll
        for (int c = 0; c < 4; c++) {
            float cn = colN[32 * c + fp];
            #pragma unroll
            for (int r = 0; r < 16; r++) {
                int r32 = (r & 3) + 8 * (r >> 2) + 4 * fh;
                float d2 = rowN[32 * g + r32] + cn - 2.0f * acc[g][c][r];
                dmin = fminf(dmin, d2);
            }
        }

    #pragma unroll
    for (int off = 32; off > 0; off >>= 1) dmin = fminf(dmin, __shfl_down(dmin, off));
    if (lane == 0) wmin[wave] = dmin;
    __syncthreads();
    if (tid == 0)
        atomicMin(&minkey[zidx],
                  float_key(fminf(fminf(wmin[0], wmin[1]), fminf(wmin[2], wmin[3]))));
}

__global__ void finalize_kernel(const double* __restrict__ accum,
                                const unsigned* __restrict__ minkey,
                                float* __restrict__ out, int N, int M) {
    if (threadIdx.x == 0 && blockIdx.x == 0) {
        float Sp[3];
        #pragma unroll
        for (int z = 0; z < 3; z++) {
            float m = key_float(minkey[z]) * (-1.0f / 512.0f);
            double Sshift = accum[z] * exp(-(double)m);
            float r = (float)log(Sshift);        // correctly-rounded f32 log
            float lse = r + m;                   // fp32 add, as jax
            Sp[z] = (float)exp((double)lse);     // correctly-rounded f32 exp
        }
        float nf  = (float)N, mf = (float)M;
        float nn1 = (float)((double)N * (double)(N - 1));
        float mm1 = (float)((double)M * (double)(M - 1));
        float nm  = (float)((double)N * (double)M);
        float xx = (Sp[0] - nf) / nn1;
        float xy =  Sp[1]       / nm;
        float yy = (Sp[2] - mf) / mm1;
        out[0] = xx - 2.0f * xy + yy;
    }
}

extern "C" void kernel_launch(void* const* d_in, const int* in_sizes, int n_in,
                              void* d_out, int out_size, void* d_ws, size_t ws_size,
                              hipStream_t stream) {
    const float* X = (const float*)d_in[0];
    const float* Y = (const float*)d_in[1];
    const int N = in_sizes[0] / D;
    const int M = in_sizes[1] / D;
    const int gx = N / BTM, gy = M / BTN;        // 64 x 32

    // ws: accum 3xf64 @0; minkey 3xu32 @32; gmin f32 @48; X2 @64; Y2;
    // bmin[gx*gy]; then 256B-aligned fp16 arrays Xh, Yh (N*D*2 B each)
    double*   accum  = (double*)d_ws;
    unsigned* minkey = (unsigned*)((char*)d_ws + 32);
    float*    gmin   = (float*)((char*)d_ws + 48);
    float*    X2     = (float*)((char*)d_ws + 64);
    float*    Y2     = X2 + N;
    float*    bmin   = Y2 + M;
    size_t off = (64 + (size_t)(N + M) * 4 + (size_t)gx * gy * 4 + 255) & ~(size_t)255;
    size_t asz = (size_t)N * D * 2;
    uint4* Xh = (uint4*)((char*)d_ws + off);
    uint4* Yh = (uint4*)((char*)d_ws + off + asz);

    hipMemsetAsync(accum, 0, 32, stream);        // zero f64 accumulators
    hipMemsetAsync(minkey, 0xFF, 16, stream);    // min-keys = UINT_MAX

    row_norms_kernel<<<(N + M + 3) / 4, 256, 0, stream>>>(X, Y, X2, Y2, N, M);
    convert_h_kernel<<<dim3((N + 255) / 256, KSTEPS), 256, 0, stream>>>(X, Xh, N);
    convert_h_kernel<<<dim3((M + 255) / 256, KSTEPS), 256, 0, stream>>>(Y, Yh, M);

    // XX/YY m: bf16-split recompute of the 128 diag-touching blocks
    refine_min_kernel<<<dim3(gx, 1), 256, 0, stream>>>(X, X, X2, X2, nullptr, nullptr,
                                                       minkey, 0, 1);
    refine_min_kernel<<<dim3(gx, 1), 256, 0, stream>>>(Y, Y, Y2, Y2, nullptr, nullptr,
                                                       minkey, 2, 1);

    dim3 grid(gx, gy, 3);
    pair_exp_sum_kernel<<<grid, 256, 0, stream>>>(Xh, Yh, X2, Y2, accum, bmin, N, M);

    // XY m: bf16-split recompute of blocks within 0.5 of global fp16 min
    xy_gmin_kernel<<<1, 256, 0, stream>>>(bmin, gmin, gx * gy);
    refine_min_kernel<<<dim3(gx, gy), 256, 0, stream>>>(X, Y, X2, Y2, bmin, gmin,
                                                        minkey, 1, 0);

    finalize_kernel<<<1, 64, 0, stream>>>(accum, minkey, (float*)d_out, N, M);
}

// Round 10
// 363.977 us; speedup vs baseline: 1.5499x; 1.1797x over previous
//
#include <hip/hip_runtime.h>
#include <math.h>

// MMD, Gaussian kernel, bandwidth=512. X:[8192,512] Y:[8192,512] fp32.
// S_AB = sum_ij exp(-||a_i-b_j||^2/512); final combine emulates the
// reference's fp32 logsumexp->exp->combine path (see finalize_kernel).
//
// Architecture (validated R9): fast fp16 single-product MFMA S-pass (S only
// needs << 1 fp32 lse cell = 17 units of 9.1e6) + bit-exact reproduction of
// the R5 bf16-split 3-product d2 min for m (the lse cell shifts with m at
// sub-ulp granularity, so m must be the exact winning bits).
// Round-10: (1) diag m via 32x32 self-tiles only (MFMA is per-element
// deterministic; same split bits + same hh/hl/lh chain -> same d2(i,i) bits;
// was 2 full-block refine kernels ~60us, now ~3us); (2) pair kernel A-frags
// direct global->VGPR (LDS was 140 B/cyc > 128 port peak; now B-only 93);
// (3) epilogue expf -> exp2f hw op (args in [-4.2,0], no edge cases).

#define D      512
#define BTM    128
#define BTN    256
#define BK     16
#define KSTEPS (D / BK)

// 16B-unit offsets in the XY refine kernel's LDS (R5 layout [point*2+khalf])
#define AHI 0
#define ALO 256
#define BHI 512
#define BLO 1024

typedef _Float16 half8 __attribute__((ext_vector_type(8)));
typedef __attribute__((ext_vector_type(8)))  short  short8;   // 8 bf16
typedef __attribute__((ext_vector_type(16))) float  f32x16;   // 32x32 acc

union U4H8 { uint4 u; half8 h; };
union U4S8 { uint4 u; short8 s; };

__device__ __forceinline__ unsigned short bf16_rne(float x) {
    unsigned u = __float_as_uint(x);
    return (unsigned short)((u + 0x7fffu + ((u >> 16) & 1u)) >> 16);
}
__device__ __forceinline__ float bf16_f32(unsigned short b) {
    return __uint_as_float(((unsigned)b) << 16);
}
__device__ __forceinline__ void split8(const float v[8], uint4& hi, uint4& lo) {
    unsigned h[8], l[8];
    #pragma unroll
    for (int j = 0; j < 8; j++) {
        unsigned short bh = bf16_rne(v[j]);
        float r = v[j] - bf16_f32(bh);          // exact (Sterbenz)
        unsigned short bl = bf16_rne(r);
        h[j] = bh; l[j] = bl;
    }
    hi.x = h[0] | (h[1] << 16); hi.y = h[2] | (h[3] << 16);
    hi.z = h[4] | (h[5] << 16); hi.w = h[6] | (h[7] << 16);
    lo.x = l[0] | (l[1] << 16); lo.y = l[2] | (l[3] << 16);
    lo.z = l[4] | (l[5] << 16); lo.w = l[6] | (l[7] << 16);
}

// async global->LDS, 16B per lane
__device__ __forceinline__ void lds16(const uint4* g, uint4* l) {
    __builtin_amdgcn_global_load_lds(
        (const __attribute__((address_space(1))) void*)g,
        (__attribute__((address_space(3))) void*)(unsigned int)(uintptr_t)(void*)l,
        16, 0, 0);
}

// fp16 convert: src[npts][512] fp32 -> [kstep][p>>5][khalf][p&31] 16B units
__global__ __launch_bounds__(256)
void convert_h_kernel(const float* __restrict__ src, uint4* __restrict__ dst, int npts) {
    const int ks = blockIdx.y;
    const int p  = blockIdx.x * 256 + threadIdx.x;
    if (p >= npts) return;
    const float* s = src + (size_t)p * D + ks * BK;
    float v[16];
    *(float4*)&v[0]  = *(const float4*)(s);
    *(float4*)&v[4]  = *(const float4*)(s + 4);
    *(float4*)&v[8]  = *(const float4*)(s + 8);
    *(float4*)&v[12] = *(const float4*)(s + 12);
    U4H8 a, b;
    #pragma unroll
    for (int j = 0; j < 8; j++) { a.h[j] = (_Float16)v[j]; b.h[j] = (_Float16)v[8 + j]; }
    size_t u = (size_t)ks * npts * 2 + (size_t)(p >> 5) * 64 + (p & 31);
    dst[u] = a.u; dst[u + 32] = b.u;
}

__global__ __launch_bounds__(256)
void row_norms_kernel(const float* __restrict__ X, const float* __restrict__ Y,
                      float* __restrict__ X2, float* __restrict__ Y2, int N, int M) {
    const int wave = threadIdx.x >> 6;
    const int lane = threadIdx.x & 63;
    const int row  = blockIdx.x * 4 + wave;
    const float* src; float* dst; int r;
    if (row < N)          { src = X; dst = X2; r = row; }
    else if (row < N + M) { src = Y; dst = Y2; r = row - N; }
    else return;
    const float* p = src + (size_t)r * D;
    float s = 0.f;
    #pragma unroll
    for (int c = 0; c < D; c += 64) {
        float v = p[c + lane];
        s = fmaf(v, v, s);
    }
    #pragma unroll
    for (int off = 32; off > 0; off >>= 1) s += __shfl_down(s, off);
    if (lane == 0) dst[r] = s;
}

__device__ inline unsigned float_key(float f) {
    unsigned u = __float_as_uint(f);
    return (u & 0x80000000u) ? ~u : (u | 0x80000000u);
}
__device__ inline float key_float(unsigned k) {
    return __uint_as_float((k & 0x80000000u) ? (k ^ 0x80000000u) : ~k);
}

// ---- XX/YY m: R5-bit-exact diag d2 via 32x32 self-tiles ------------------
// MFMA D[i][j] depends only on A row i, B col j, and the C chain: the diag
// element (i,i) of R5's d2 field is reproduced bit-exactly by running the
// same split8 + hh,hl,lh chained 32x32x16 MFMAs on the 32-point group
// containing i, with A-frag == B-frag. Off-diag d2 >= ~650 cannot be min.
// One wave per 32-point group.
__global__ __launch_bounds__(256)
void diag_min_bits_kernel(const float* __restrict__ src, const float* __restrict__ n2,
                          unsigned* __restrict__ minkey, int zidx) {
    const int tid  = threadIdx.x;
    const int wave = tid >> 6, lane = tid & 63;
    const int grp  = blockIdx.x * 4 + wave;       // 32-point group id
    const int fp   = lane & 31, fh = lane >> 5;
    const int pt   = grp * 32 + fp;
    const float* s = src + (size_t)pt * D + fh * 8;

    f32x16 acc;
    #pragma unroll
    for (int i = 0; i < 16; i++) acc[i] = 0.f;

    for (int ks = 0; ks < KSTEPS; ks++) {
        float v[8];
        *(float4*)&v[0] = *(const float4*)(s + ks * BK);
        *(float4*)&v[4] = *(const float4*)(s + ks * BK + 4);
        U4S8 hi, lo;
        split8(v, hi.u, lo.u);
        short8 ah = hi.s, al = lo.s;
        // R5 order: hh, h*lB, lA*h (A-frag == B-frag here)
        acc = __builtin_amdgcn_mfma_f32_32x32x16_bf16(ah, ah, acc, 0, 0, 0);
        acc = __builtin_amdgcn_mfma_f32_32x32x16_bf16(ah, al, acc, 0, 0, 0);
        acc = __builtin_amdgcn_mfma_f32_32x32x16_bf16(al, ah, acc, 0, 0, 0);
    }

    // diag element (fp,fp): row fp held by lane iff fh == (fp>>2)&1, at
    // reg r with (r&3)=fp&3, (r>>2)=fp>>3  (row=(r&3)+8*(r>>2)+4*fh)
    float dmin = 1e30f;
    if (fh == ((fp >> 2) & 1)) {
        int r = (fp & 3) + 4 * (fp >> 3);
        float av = acc[r];
        float rn = n2[pt];
        float cn = rn;
        float d2 = rn + cn - 2.0f * av;           // 2*av & rn+cn exact: contraction-safe
        dmin = d2;
    }
    #pragma unroll
    for (int off = 32; off > 0; off >>= 1) dmin = fminf(dmin, __shfl_down(dmin, off));
    __shared__ float wm[4];
    if (lane == 0) wm[wave] = dmin;
    __syncthreads();
    if (tid == 0)
        atomicMin(&minkey[zidx],
                  float_key(fminf(fminf(wm[0], wm[1]), fminf(wm[2], wm[3]))));
}

// ---------- fp16 S-pass: grid (64,32,3): z=0 XX (sym), 1 XY, 2 YY ----------
struct AF { half8 h[2]; };

__global__ __launch_bounds__(256, 2)
void pair_exp_sum_kernel(const uint4* __restrict__ Xh, const uint4* __restrict__ Yh,
                         const float* __restrict__ X2, const float* __restrict__ Y2,
                         double* __restrict__ accum, float* __restrict__ bmin,
                         int N, int M) {
    const int z = blockIdx.z;
    const uint4 *Ah, *Bh; const float *An, *Bn; bool sym; int na, nb;
    if (z == 0)      { Ah = Xh; Bh = Xh; An = X2; Bn = X2; sym = true;  na = N; nb = N; }
    else if (z == 1) { Ah = Xh; Bh = Yh; An = X2; Bn = Y2; sym = false; na = N; nb = M; }
    else             { Ah = Yh; Bh = Yh; An = Y2; Bn = Y2; sym = true;  na = M; nb = M; }
    const int bi = blockIdx.x, bj = blockIdx.y;
    if (sym && (2 * bj + 1) < bi) return;        // both 128-col halves below diag

    __shared__ uint4  smem[2][512];              // B only: 2 x 8 KB
    __shared__ float  smN[BTM + BTN];
    __shared__ double wsum[4];
    __shared__ float  wmin[4];

    const int tid  = threadIdx.x;
    const int wave = tid >> 6, lane = tid & 63;
    const int wy = wave >> 1, wx = wave & 1;     // 2x2 waves, each 64x128
    const int row0 = bi * BTM, col0 = bj * BTN;

    if (tid < BTM) smN[tid] = An[row0 + tid];
    smN[BTM + tid] = Bn[col0 + tid];

    const int wl = wave * 64 + lane;
    const size_t strideA = (size_t)na * 2;       // 16B units per kstep
    const size_t strideB = (size_t)nb * 2;
    const uint4* gB0 = Bh + (size_t)(col0 >> 5) * 64 + wl;
    const uint4* gB1 = gB0 + 256;
    // A frag direct-load pointers (short8 units; coalesced 1 KB/wave)
    const half8* gA0 = (const half8*)Ah + ((size_t)(row0 >> 5) + 2 * wy) * 64 + lane;
    const half8* gA1 = gA0 + 64;

    f32x16 acc[2][4];
    #pragma unroll
    for (int g = 0; g < 2; g++)
        #pragma unroll
        for (int c = 0; c < 4; c++)
            #pragma unroll
            for (int i = 0; i < 16; i++) acc[g][c][i] = 0.f;

    auto stage = [&](int buf, int ks) {          // 8 KB via 2 DMAs/thread
        lds16(gB0 + (size_t)ks * strideB, &smem[buf][wl]);
        lds16(gB1 + (size_t)ks * strideB, &smem[buf][256 + wl]);
    };
    auto loadA = [&](int ks, AF& f) {
        f.h[0] = gA0[(size_t)ks * strideA];
        f.h[1] = gA1[(size_t)ks * strideA];
    };
    auto compute = [&](int buf, const AF& a) {
        const half8* p = (const half8*)&smem[buf][0];
        half8 bh[4];
        #pragma unroll
        for (int c = 0; c < 4; c++) bh[c] = p[(4 * wx + c) * 64 + lane];
        #pragma unroll
        for (int g = 0; g < 2; g++)
            #pragma unroll
            for (int c = 0; c < 4; c++)
                acc[g][c] = __builtin_amdgcn_mfma_f32_32x32x16_f16(a.h[g], bh[c], acc[g][c], 0, 0, 0);
    };

    AF A0, A1;
    stage(0, 0);
    loadA(0, A0);
    __syncthreads();

    for (int ks = 1; ks < KSTEPS - 1; ks += 2) {
        stage(1, ks);      loadA(ks, A1);
        compute(0, A0);
        __syncthreads();
        stage(0, ks + 1);  loadA(ks + 1, A0);
        compute(1, A1);
        __syncthreads();
    }
    stage(1, KSTEPS - 1);  loadA(KSTEPS - 1, A1);
    compute(0, A0);
    __syncthreads();
    compute(1, A1);

    float wgt = 1.f;
    if (sym) {
        int cblk = 2 * bj + wx;
        wgt = (cblk > bi) ? 2.f : (cblk == bi ? 1.f : 0.f);
    }

    // C/D layout (m74/m101): col=lane&31, row=(reg&3)+8*(reg>>2)+4*(lane>>5)
    const int fp = lane & 31, fh = lane >> 5;
    double s = 0.0;
    float dmin = 1e30f;
    if (wgt != 0.f) {
        const float* rowN = &smN[64 * wy];
        const float* colN = &smN[BTM + 128 * wx];
        const float kC = -0.0028177637517362567f;   // -log2(e)/512
        #pragma unroll
        for (int g = 0; g < 2; g++)
            #pragma unroll
            for (int c = 0; c < 4; c++) {
                float cn = colN[32 * c + fp];
                float rs = 0.f;
                #pragma unroll
                for (int r = 0; r < 16; r++) {
                    int r32 = (r & 3) + 8 * (r >> 2) + 4 * fh;
                    float d2 = rowN[32 * g + r32] + cn - 2.0f * acc[g][c][r];
                    dmin = fminf(dmin, d2);
                    rs += exp2f(d2 * kC);            // v_exp_f32; args in [-4.2,0]
                }
                s += (double)rs;
            }
        s *= (double)wgt;
    }

    #pragma unroll
    for (int off = 32; off > 0; off >>= 1) {
        s += __shfl_down(s, off);
        dmin = fminf(dmin, __shfl_down(dmin, off));
    }
    if (lane == 0) { wsum[wave] = s; wmin[wave] = dmin; }
    __syncthreads();
    if (tid == 0) {
        atomicAdd(&accum[z], wsum[0] + wsum[1] + wsum[2] + wsum[3]);
        if (z == 1)                              // noisy (+-~0.05) block min
            bmin[bi * gridDim.y + bj] = fminf(fminf(wmin[0], wmin[1]),
                                              fminf(wmin[2], wmin[3]));
    }
}

__global__ __launch_bounds__(256)
void xy_gmin_kernel(const float* __restrict__ bmin, float* __restrict__ gmin, int nblk) {
    float m = 1e30f;
    for (int i = threadIdx.x; i < nblk; i += 256) m = fminf(m, bmin[i]);
    #pragma unroll
    for (int off = 32; off > 0; off >>= 1) m = fminf(m, __shfl_down(m, off));
    __shared__ float wm[4];
    if ((threadIdx.x & 63) == 0) wm[threadIdx.x >> 6] = m;
    __syncthreads();
    if (threadIdx.x == 0) gmin[0] = fminf(fminf(wm[0], wm[1]), fminf(wm[2], wm[3]));
}

// ---------- XY refine: R5-bit-exact bf16-split 3-product d2 min -----------
// grid(64,32); computes only blocks within 0.5 of the global fp16 min
// (fp16 noise sigma ~0.05). Verbatim R9 body (validated bits).
__global__ __launch_bounds__(256)
void refine_min_kernel(const float* __restrict__ A, const float* __restrict__ B,
                       const float* __restrict__ An, const float* __restrict__ Bn,
                       const float* __restrict__ bmin, const float* __restrict__ gmin,
                       unsigned* __restrict__ minkey, int zidx) {
    const int bi = blockIdx.x;
    const int bj = blockIdx.y;
    if (!(bmin[bi * gridDim.y + bj] < gmin[0] + 0.5f)) return;
    const int row0 = bi * BTM, col0 = bj * BTN;

    __shared__ uint4 smem[1536];                 // Ahi|Alo|Bhi|Blo (R5 layout)
    __shared__ float smN[BTM + BTN];
    __shared__ float wmin[4];

    const int tid  = threadIdx.x;
    const int wave = tid >> 6, lane = tid & 63;
    const int wy = wave >> 1, wx = wave & 1;
    if (tid < BTM) smN[tid] = An[row0 + tid];
    smN[BTM + tid] = Bn[col0 + tid];

    const int fp = lane & 31, fh = lane >> 5;
    int au[2], bu[4];
    #pragma unroll
    for (int g = 0; g < 2; g++) au[g] = (64 * wy + 32 * g + fp) * 2 + fh;
    #pragma unroll
    for (int c = 0; c < 4; c++) bu[c] = (128 * wx + 32 * c + fp) * 2 + fh;

    f32x16 acc[2][4];
    #pragma unroll
    for (int g = 0; g < 2; g++)
        #pragma unroll
        for (int c = 0; c < 4; c++)
            #pragma unroll
            for (int i = 0; i < 16; i++) acc[g][c][i] = 0.f;

    for (int ks = 0; ks < KSTEPS; ks++) {
        __syncthreads();                         // prev-step LDS reads done
        {   // A: unit tid (point tid>>1, khalf tid&1)
            const float* s = A + (size_t)(row0 + (tid >> 1)) * D + ks * BK + (tid & 1) * 8;
            float v[8];
            *(float4*)&v[0] = *(const float4*)s;
            *(float4*)&v[4] = *(const float4*)(s + 4);
            uint4 hi, lo; split8(v, hi, lo);
            smem[AHI + tid] = hi; smem[ALO + tid] = lo;
        }
        #pragma unroll
        for (int t = 0; t < 2; t++) {            // B: units tid, tid+256
            int u = tid + t * 256;
            const float* s = B + (size_t)(col0 + (u >> 1)) * D + ks * BK + (u & 1) * 8;
            float v[8];
            *(float4*)&v[0] = *(const float4*)s;
            *(float4*)&v[4] = *(const float4*)(s + 4);
            uint4 hi, lo; split8(v, hi, lo);
            smem[BHI + u] = hi; smem[BLO + u] = lo;
        }
        __syncthreads();
        {   // R5 compute, verbatim order: all hh, all hl, all lh
            const short8* p = (const short8*)&smem[0];
            short8 ah[2], al[2], bh[4], bl[4];
            #pragma unroll
            for (int g = 0; g < 2; g++) { ah[g] = p[AHI + au[g]]; al[g] = p[ALO + au[g]]; }
            #pragma unroll
            for (int c = 0; c < 4; c++) { bh[c] = p[BHI + bu[c]]; bl[c] = p[BLO + bu[c]]; }
            #pragma unroll
            for (int g = 0; g < 2; g++)
                #pragma unroll
                for (int c = 0; c < 4; c++)
                    acc[g][c] = __builtin_amdgcn_mfma_f32_32x32x16_bf16(ah[g], bh[c], acc[g][c], 0, 0, 0);
            #pragma unroll
            for (int g = 0; g < 2; g++)
                #pragma unroll
                for (int c = 0; c < 4; c++)
                    acc[g][c] = __builtin_amdgcn_mfma_f32_32x32x16_bf16(ah[g], bl[c], acc[g][c], 0, 0, 0);
            #pragma unroll
            for (int g = 0; g < 2; g++)
                #pragma unroll
                for (int c = 0; c < 4; c++)
                    acc[g][c] = __builtin_amdgcn_mfma_f32_32x32x16_bf16(al[g], bh[c], acc[g][c], 0, 0, 0);
        }
    }

    float dmin = 1e30f;
    const float* rowN = &smN[64 * wy];
    const float* colN = &smN[BTM + 128 * wx];
    #pragma unroll
    for (int g = 0; g < 2; g++)
        #pragma unroll
        for (int c = 0; c < 4; c++) {
            float cn = colN[32 * c + fp];
            #pragma unroll
            for (int r = 0; r < 16; r++) {
                int r32 = (r & 3) + 8 * (r >> 2) + 4 * fh;
                float d2 = rowN[32 * g + r32] + cn - 2.0f * acc[g][c][r];
                dmin = fminf(dmin, d2);
            }
        }

    #pragma unroll
    for (int off = 32; off > 0; off >>= 1) dmin = fminf(dmin, __shfl_down(dmin, off));
    if (lane == 0) wmin[wave] = dmin;
    __syncthreads();
    if (tid == 0)
        atomicMin(&minkey[zidx],
                  float_key(fminf(fminf(wmin[0], wmin[1]), fminf(wmin[2], wmin[3]))));
}

__global__ void finalize_kernel(const double* __restrict__ accum,
                                const unsigned* __restrict__ minkey,
                                float* __restrict__ out, int N, int M) {
    if (threadIdx.x == 0 && blockIdx.x == 0) {
        float Sp[3];
        #pragma unroll
        for (int z = 0; z < 3; z++) {
            float m = key_float(minkey[z]) * (-1.0f / 512.0f);
            double Sshift = accum[z] * exp(-(double)m);
            float r = (float)log(Sshift);        // correctly-rounded f32 log
            float lse = r + m;                   // fp32 add, as jax
            Sp[z] = (float)exp((double)lse);     // correctly-rounded f32 exp
        }
        float nf  = (float)N, mf = (float)M;
        float nn1 = (float)((double)N * (double)(N - 1));
        float mm1 = (float)((double)M * (double)(M - 1));
        float nm  = (float)((double)N * (double)M);
        float xx = (Sp[0] - nf) / nn1;
        float xy =  Sp[1]       / nm;
        float yy = (Sp[2] - mf) / mm1;
        out[0] = xx - 2.0f * xy + yy;
    }
}

extern "C" void kernel_launch(void* const* d_in, const int* in_sizes, int n_in,
                              void* d_out, int out_size, void* d_ws, size_t ws_size,
                              hipStream_t stream) {
    const float* X = (const float*)d_in[0];
    const float* Y = (const float*)d_in[1];
    const int N = in_sizes[0] / D;
    const int M = in_sizes[1] / D;
    const int gx = N / BTM, gy = M / BTN;        // 64 x 32

    // ws: accum 3xf64 @0; minkey 3xu32 @32; gmin f32 @48; X2 @64; Y2;
    // bmin[gx*gy]; then 256B-aligned fp16 arrays Xh, Yh (N*D*2 B each)
    double*   accum  = (double*)d_ws;
    unsigned* minkey = (unsigned*)((char*)d_ws + 32);
    float*    gmin   = (float*)((char*)d_ws + 48);
    float*    X2     = (float*)((char*)d_ws + 64);
    float*    Y2     = X2 + N;
    float*    bmin   = Y2 + M;
    size_t off = (64 + (size_t)(N + M) * 4 + (size_t)gx * gy * 4 + 255) & ~(size_t)255;
    size_t asz = (size_t)N * D * 2;
    uint4* Xh = (uint4*)((char*)d_ws + off);
    uint4* Yh = (uint4*)((char*)d_ws + off + asz);

    hipMemsetAsync(accum, 0, 32, stream);        // zero f64 accumulators
    hipMemsetAsync(minkey, 0xFF, 16, stream);    // min-keys = UINT_MAX

    row_norms_kernel<<<(N + M + 3) / 4, 256, 0, stream>>>(X, Y, X2, Y2, N, M);
    convert_h_kernel<<<dim3((N + 255) / 256, KSTEPS), 256, 0, stream>>>(X, Xh, N);
    convert_h_kernel<<<dim3((M + 255) / 256, KSTEPS), 256, 0, stream>>>(Y, Yh, M);

    // XX/YY m: bit-exact diag d2 via 32x32 self-tiles (1 wave / 32 points)
    diag_min_bits_kernel<<<N / 128, 256, 0, stream>>>(X, X2, minkey, 0);
    diag_min_bits_kernel<<<M / 128, 256, 0, stream>>>(Y, Y2, minkey, 2);

    dim3 grid(gx, gy, 3);
    pair_exp_sum_kernel<<<grid, 256, 0, stream>>>(Xh, Yh, X2, Y2, accum, bmin, N, M);

    // XY m: bf16-split recompute of blocks within 0.5 of global fp16 min
    xy_gmin_kernel<<<1, 256, 0, stream>>>(bmin, gmin, gx * gy);
    refine_min_kernel<<<dim3(gx, gy), 256, 0, stream>>>(X, Y, X2, Y2, bmin, gmin,
                                                        minkey, 1);

    finalize_kernel<<<1, 64, 0, stream>>>(accum, minkey, (float*)d_out, N, M);
}

// Round 11
// 324.769 us; speedup vs baseline: 1.7371x; 1.1207x over previous
//
#include <hip/hip_runtime.h>
#include <math.h>

// MMD, Gaussian kernel, bandwidth=512. X:[8192,512] Y:[8192,512] fp32.
// S_AB = sum_ij exp(-||a_i-b_j||^2/512); final combine emulates the
// reference's fp32 logsumexp->exp->combine path (see finalize_kernel).
//
// Architecture (validated R9/R10): fp16 single-product MFMA S-pass (S needs
// << 1 fp32 lse cell = 17 units of 9.1e6) + bit-exact reproduction of the
// R5 bf16-split 3-product d2 min for m (lse cell shifts with m at sub-ulp
// granularity -> m must be the exact winning bits; XX/YY via 32x32 diag
// self-tiles, XY via banded refine).
// Round-11: pair kernel stages TWO k-steps (16 KB) per LDS buffer -> one
// barrier per 64 CU-MFMAs (was 32). R10 measured ~990 cyc/step vs 258 cyc
// MFMA: the vmcnt(0)+s_barrier drain of the just-issued DMA dominated;
// doubling the interval gives 516 cyc of compute cover >= L2/L3 latency
// and halves barrier count. Per-element MFMA chain order unchanged ->
// all sums/mins bit-identical to R10. Aux: converts fused (z-dim), diag
// kernels fused, memsets -> 1 init kernel (11 -> 8 graph nodes).

#define D      512
#define BTM    128
#define BTN    256
#define BK     16
#define KSTEPS (D / BK)

// 16B-unit offsets in the XY refine kernel's LDS (R5 layout [point*2+khalf])
#define AHI 0
#define ALO 256
#define BHI 512
#define BLO 1024

typedef _Float16 half8 __attribute__((ext_vector_type(8)));
typedef __attribute__((ext_vector_type(8)))  short  short8;   // 8 bf16
typedef __attribute__((ext_vector_type(16))) float  f32x16;   // 32x32 acc

union U4H8 { uint4 u; half8 h; };
union U4S8 { uint4 u; short8 s; };

__device__ __forceinline__ unsigned short bf16_rne(float x) {
    unsigned u = __float_as_uint(x);
    return (unsigned short)((u + 0x7fffu + ((u >> 16) & 1u)) >> 16);
}
__device__ __forceinline__ float bf16_f32(unsigned short b) {
    return __uint_as_float(((unsigned)b) << 16);
}
__device__ __forceinline__ void split8(const float v[8], uint4& hi, uint4& lo) {
    unsigned h[8], l[8];
    #pragma unroll
    for (int j = 0; j < 8; j++) {
        unsigned short bh = bf16_rne(v[j]);
        float r = v[j] - bf16_f32(bh);          // exact (Sterbenz)
        unsigned short bl = bf16_rne(r);
        h[j] = bh; l[j] = bl;
    }
    hi.x = h[0] | (h[1] << 16); hi.y = h[2] | (h[3] << 16);
    hi.z = h[4] | (h[5] << 16); hi.w = h[6] | (h[7] << 16);
    lo.x = l[0] | (l[1] << 16); lo.y = l[2] | (l[3] << 16);
    lo.z = l[4] | (l[5] << 16); lo.w = l[6] | (l[7] << 16);
}

// async global->LDS, 16B per lane
__device__ __forceinline__ void lds16(const uint4* g, uint4* l) {
    __builtin_amdgcn_global_load_lds(
        (const __attribute__((address_space(1))) void*)g,
        (__attribute__((address_space(3))) void*)(unsigned int)(uintptr_t)(void*)l,
        16, 0, 0);
}

__global__ void init_kernel(double* accum, unsigned* minkey) {
    if (threadIdx.x < 3) accum[threadIdx.x] = 0.0;
    if (threadIdx.x < 4) minkey[threadIdx.x] = 0xFFFFFFFFu;
}

// fp16 convert: src[npts][512] fp32 -> [kstep][p>>5][khalf][p&31] 16B units
// z=0: X->Xh, z=1: Y->Yh (per-element arithmetic identical to R10)
__global__ __launch_bounds__(256)
void convert_h_kernel(const float* __restrict__ X, const float* __restrict__ Y,
                      uint4* __restrict__ Xh, uint4* __restrict__ Yh, int npts) {
    const float* src = blockIdx.z ? Y : X;
    uint4*       dst = blockIdx.z ? Yh : Xh;
    const int ks = blockIdx.y;
    const int p  = blockIdx.x * 256 + threadIdx.x;
    if (p >= npts) return;
    const float* s = src + (size_t)p * D + ks * BK;
    float v[16];
    *(float4*)&v[0]  = *(const float4*)(s);
    *(float4*)&v[4]  = *(const float4*)(s + 4);
    *(float4*)&v[8]  = *(const float4*)(s + 8);
    *(float4*)&v[12] = *(const float4*)(s + 12);
    U4H8 a, b;
    #pragma unroll
    for (int j = 0; j < 8; j++) { a.h[j] = (_Float16)v[j]; b.h[j] = (_Float16)v[8 + j]; }
    size_t u = (size_t)ks * npts * 2 + (size_t)(p >> 5) * 64 + (p & 31);
    dst[u] = a.u; dst[u + 32] = b.u;
}

__global__ __launch_bounds__(256)
void row_norms_kernel(const float* __restrict__ X, const float* __restrict__ Y,
                      float* __restrict__ X2, float* __restrict__ Y2, int N, int M) {
    const int wave = threadIdx.x >> 6;
    const int lane = threadIdx.x & 63;
    const int row  = blockIdx.x * 4 + wave;
    const float* src; float* dst; int r;
    if (row < N)          { src = X; dst = X2; r = row; }
    else if (row < N + M) { src = Y; dst = Y2; r = row - N; }
    else return;
    const float* p = src + (size_t)r * D;
    float s = 0.f;
    #pragma unroll
    for (int c = 0; c < D; c += 64) {
        float v = p[c + lane];
        s = fmaf(v, v, s);
    }
    #pragma unroll
    for (int off = 32; off > 0; off >>= 1) s += __shfl_down(s, off);
    if (lane == 0) dst[r] = s;
}

__device__ inline unsigned float_key(float f) {
    unsigned u = __float_as_uint(f);
    return (u & 0x80000000u) ? ~u : (u | 0x80000000u);
}
__device__ inline float key_float(unsigned k) {
    return __uint_as_float((k & 0x80000000u) ? (k ^ 0x80000000u) : ~k);
}

// ---- XX/YY m: R5-bit-exact diag d2 via 32x32 self-tiles (fused X+Y) ------
// One wave per 32-point group; per-wave computation identical to R10.
__global__ __launch_bounds__(256)
void diag_min_bits_kernel(const float* __restrict__ X, const float* __restrict__ Y,
                          const float* __restrict__ X2, const float* __restrict__ Y2,
                          unsigned* __restrict__ minkey, int ngx) {
    int b = blockIdx.x;
    const float *src, *n2; int zidx;
    if (b < ngx) { src = X; n2 = X2; zidx = 0; }
    else         { src = Y; n2 = Y2; zidx = 2; b -= ngx; }

    const int tid  = threadIdx.x;
    const int wave = tid >> 6, lane = tid & 63;
    const int grp  = b * 4 + wave;                // 32-point group id
    const int fp   = lane & 31, fh = lane >> 5;
    const int pt   = grp * 32 + fp;
    const float* s = src + (size_t)pt * D + fh * 8;

    f32x16 acc;
    #pragma unroll
    for (int i = 0; i < 16; i++) acc[i] = 0.f;

    for (int ks = 0; ks < KSTEPS; ks++) {
        float v[8];
        *(float4*)&v[0] = *(const float4*)(s + ks * BK);
        *(float4*)&v[4] = *(const float4*)(s + ks * BK + 4);
        U4S8 hi, lo;
        split8(v, hi.u, lo.u);
        short8 ah = hi.s, al = lo.s;
        // R5 order: hh, h*lB, lA*h (A-frag == B-frag here)
        acc = __builtin_amdgcn_mfma_f32_32x32x16_bf16(ah, ah, acc, 0, 0, 0);
        acc = __builtin_amdgcn_mfma_f32_32x32x16_bf16(ah, al, acc, 0, 0, 0);
        acc = __builtin_amdgcn_mfma_f32_32x32x16_bf16(al, ah, acc, 0, 0, 0);
    }

    float dmin = 1e30f;
    if (fh == ((fp >> 2) & 1)) {
        int r = (fp & 3) + 4 * (fp >> 3);
        float av = acc[r];
        float rn = n2[pt];
        float cn = rn;
        float d2 = rn + cn - 2.0f * av;           // exact: contraction-safe
        dmin = d2;
    }
    #pragma unroll
    for (int off = 32; off > 0; off >>= 1) dmin = fminf(dmin, __shfl_down(dmin, off));
    __shared__ float wm[4];
    __shared__ int   wz[4];
    if (lane == 0) { wm[wave] = dmin; wz[wave] = zidx; }
    __syncthreads();
    if (tid == 0)                                  // all 4 waves share zidx
        atomicMin(&minkey[wz[0]],
                  float_key(fminf(fminf(wm[0], wm[1]), fminf(wm[2], wm[3]))));
}

// ---------- fp16 S-pass: grid (64,32,3): z=0 XX (sym), 1 XY, 2 YY ----------
__global__ __launch_bounds__(256, 2)
void pair_exp_sum_kernel(const uint4* __restrict__ Xh, const uint4* __restrict__ Yh,
                         const float* __restrict__ X2, const float* __restrict__ Y2,
                         double* __restrict__ accum, float* __restrict__ bmin,
                         int N, int M) {
    const int z = blockIdx.z;
    const uint4 *Ah, *Bh; const float *An, *Bn; bool sym; int na, nb;
    if (z == 0)      { Ah = Xh; Bh = Xh; An = X2; Bn = X2; sym = true;  na = N; nb = N; }
    else if (z == 1) { Ah = Xh; Bh = Yh; An = X2; Bn = Y2; sym = false; na = N; nb = M; }
    else             { Ah = Yh; Bh = Yh; An = Y2; Bn = Y2; sym = true;  na = M; nb = M; }
    const int bi = blockIdx.x, bj = blockIdx.y;
    if (sym && (2 * bj + 1) < bi) return;        // both 128-col halves below diag

    __shared__ uint4  smem[2][1024];             // 2 bufs x 16 KB (2 ksteps each)
    __shared__ float  smN[BTM + BTN];
    __shared__ double wsum[4];
    __shared__ float  wmin[4];

    const int tid  = threadIdx.x;
    const int wave = tid >> 6, lane = tid & 63;
    const int wy = wave >> 1, wx = wave & 1;     // 2x2 waves, each 64x128
    const int row0 = bi * BTM, col0 = bj * BTN;

    if (tid < BTM) smN[tid] = An[row0 + tid];
    smN[BTM + tid] = Bn[col0 + tid];

    const int wl = wave * 64 + lane;
    const size_t strideA = (size_t)na * 2;       // 16B units per kstep
    const size_t strideB = (size_t)nb * 2;
    const uint4* gB0 = Bh + (size_t)(col0 >> 5) * 64 + wl;
    const uint4* gB1 = gB0 + 256;
    const half8* gA0 = (const half8*)Ah + ((size_t)(row0 >> 5) + 2 * wy) * 64 + lane;
    const half8* gA1 = gA0 + 64;

    f32x16 acc[2][4];
    #pragma unroll
    for (int g = 0; g < 2; g++)
        #pragma unroll
        for (int c = 0; c < 4; c++)
            #pragma unroll
            for (int i = 0; i < 16; i++) acc[g][c][i] = 0.f;

    // stage TWO k-steps (16 KB) into one buffer: [0..511]=ks, [512..1023]=ks+1
    auto stage2 = [&](int buf, int ks) {
        lds16(gB0 + (size_t)ks * strideB,       &smem[buf][wl]);
        lds16(gB1 + (size_t)ks * strideB,       &smem[buf][256 + wl]);
        lds16(gB0 + (size_t)(ks + 1) * strideB, &smem[buf][512 + wl]);
        lds16(gB1 + (size_t)(ks + 1) * strideB, &smem[buf][768 + wl]);
    };
    half8 Af[4][2];                              // [slot][g]; slots ping-pong by 2
    auto loadA2 = [&](int ks, int s) {
        Af[s][0]     = gA0[(size_t)ks * strideA];
        Af[s][1]     = gA1[(size_t)ks * strideA];
        Af[s + 1][0] = gA0[(size_t)(ks + 1) * strideA];
        Af[s + 1][1] = gA1[(size_t)(ks + 1) * strideA];
    };
    auto computeK = [&](const uint4* base, int slot) {   // one kstep
        const half8* p = (const half8*)base;
        half8 bh[4];
        #pragma unroll
        for (int c = 0; c < 4; c++) bh[c] = p[(4 * wx + c) * 64 + lane];
        #pragma unroll
        for (int g = 0; g < 2; g++)
            #pragma unroll
            for (int c = 0; c < 4; c++)
                acc[g][c] = __builtin_amdgcn_mfma_f32_32x32x16_f16(Af[slot][g], bh[c], acc[g][c], 0, 0, 0);
    };

    stage2(0, 0);
    loadA2(0, 0);
    __syncthreads();

    #pragma unroll
    for (int it = 1; it < KSTEPS / 2; it++) {    // 15 intervals
        stage2(it & 1, 2 * it);                  // prefetch next pair
        loadA2(2 * it, (it & 1) * 2);
        computeK(&smem[(it - 1) & 1][0],   ((it - 1) & 1) * 2);      // kstep 2it-2
        computeK(&smem[(it - 1) & 1][512], ((it - 1) & 1) * 2 + 1);  // kstep 2it-1
        __syncthreads();                         // drains DMAs issued this interval
    }
    computeK(&smem[1][0],   2);                  // ksteps 30,31
    computeK(&smem[1][512], 3);

    float wgt = 1.f;
    if (sym) {
        int cblk = 2 * bj + wx;
        wgt = (cblk > bi) ? 2.f : (cblk == bi ? 1.f : 0.f);
    }

    // C/D layout (m74/m101): col=lane&31, row=(reg&3)+8*(reg>>2)+4*(lane>>5)
    const int fp = lane & 31, fh = lane >> 5;
    double s = 0.0;
    float dmin = 1e30f;
    if (wgt != 0.f) {
        const float* rowN = &smN[64 * wy];
        const float* colN = &smN[BTM + 128 * wx];
        const float kC = -0.0028177637517362567f;   // -log2(e)/512
        #pragma unroll
        for (int g = 0; g < 2; g++)
            #pragma unroll
            for (int c = 0; c < 4; c++) {
                float cn = colN[32 * c + fp];
                float rs = 0.f;
                #pragma unroll
                for (int r = 0; r < 16; r++) {
                    int r32 = (r & 3) + 8 * (r >> 2) + 4 * fh;
                    float d2 = rowN[32 * g + r32] + cn - 2.0f * acc[g][c][r];
                    dmin = fminf(dmin, d2);
                    rs += exp2f(d2 * kC);            // v_exp_f32; args in [-4.2,0]
                }
                s += (double)rs;
            }
        s *= (double)wgt;
    }

    #pragma unroll
    for (int off = 32; off > 0; off >>= 1) {
        s += __shfl_down(s, off);
        dmin = fminf(dmin, __shfl_down(dmin, off));
    }
    if (lane == 0) { wsum[wave] = s; wmin[wave] = dmin; }
    __syncthreads();
    if (tid == 0) {
        atomicAdd(&accum[z], wsum[0] + wsum[1] + wsum[2] + wsum[3]);
        if (z == 1)                              // noisy (+-~0.05) block min
            bmin[bi * gridDim.y + bj] = fminf(fminf(wmin[0], wmin[1]),
                                              fminf(wmin[2], wmin[3]));
    }
}

__global__ __launch_bounds__(256)
void xy_gmin_kernel(const float* __restrict__ bmin, float* __restrict__ gmin, int nblk) {
    float m = 1e30f;
    for (int i = threadIdx.x; i < nblk; i += 256) m = fminf(m, bmin[i]);
    #pragma unroll
    for (int off = 32; off > 0; off >>= 1) m = fminf(m, __shfl_down(m, off));
    __shared__ float wm[4];
    if ((threadIdx.x & 63) == 0) wm[threadIdx.x >> 6] = m;
    __syncthreads();
    if (threadIdx.x == 0) gmin[0] = fminf(fminf(wm[0], wm[1]), fminf(wm[2], wm[3]));
}

// ---------- XY refine: R5-bit-exact bf16-split 3-product d2 min -----------
__global__ __launch_bounds__(256)
void refine_min_kernel(const float* __restrict__ A, const float* __restrict__ B,
                       const float* __restrict__ An, const float* __restrict__ Bn,
                       const float* __restrict__ bmin, const float* __restrict__ gmin,
                       unsigned* __restrict__ minkey, int zidx) {
    const int bi = blockIdx.x;
    const int bj = blockIdx.y;
    if (!(bmin[bi * gridDim.y + bj] < gmin[0] + 0.5f)) return;
    const int row0 = bi * BTM, col0 = bj * BTN;

    __shared__ uint4 smem[1536];                 // Ahi|Alo|Bhi|Blo (R5 layout)
    __shared__ float smN[BTM + BTN];
    __shared__ float wmin[4];

    const int tid  = threadIdx.x;
    const int wave = tid >> 6, lane = tid & 63;
    const int wy = wave >> 1, wx = wave & 1;
    if (tid < BTM) smN[tid] = An[row0 + tid];
    smN[BTM + tid] = Bn[col0 + tid];

    const int fp = lane & 31, fh = lane >> 5;
    int au[2], bu[4];
    #pragma unroll
    for (int g = 0; g < 2; g++) au[g] = (64 * wy + 32 * g + fp) * 2 + fh;
    #pragma unroll
    for (int c = 0; c < 4; c++) bu[c] = (128 * wx + 32 * c + fp) * 2 + fh;

    f32x16 acc[2][4];
    #pragma unroll
    for (int g = 0; g < 2; g++)
        #pragma unroll
        for (int c = 0; c < 4; c++)
            #pragma unroll
            for (int i = 0; i < 16; i++) acc[g][c][i] = 0.f;

    for (int ks = 0; ks < KSTEPS; ks++) {
        __syncthreads();                         // prev-step LDS reads done
        {   // A: unit tid (point tid>>1, khalf tid&1)
            const float* s = A + (size_t)(row0 + (tid >> 1)) * D + ks * BK + (tid & 1) * 8;
            float v[8];
            *(float4*)&v[0] = *(const float4*)s;
            *(float4*)&v[4] = *(const float4*)(s + 4);
            uint4 hi, lo; split8(v, hi, lo);
            smem[AHI + tid] = hi; smem[ALO + tid] = lo;
        }
        #pragma unroll
        for (int t = 0; t < 2; t++) {            // B: units tid, tid+256
            int u = tid + t * 256;
            const float* s = B + (size_t)(col0 + (u >> 1)) * D + ks * BK + (u & 1) * 8;
            float v[8];
            *(float4*)&v[0] = *(const float4*)s;
            *(float4*)&v[4] = *(const float4*)(s + 4);
            uint4 hi, lo; split8(v, hi, lo);
            smem[BHI + u] = hi; smem[BLO + u] = lo;
        }
        __syncthreads();
        {   // R5 compute, verbatim order: all hh, all hl, all lh
            const short8* p = (const short8*)&smem[0];
            short8 ah[2], al[2], bh[4], bl[4];
            #pragma unroll
            for (int g = 0; g < 2; g++) { ah[g] = p[AHI + au[g]]; al[g] = p[ALO + au[g]]; }
            #pragma unroll
            for (int c = 0; c < 4; c++) { bh[c] = p[BHI + bu[c]]; bl[c] = p[BLO + bu[c]]; }
            #pragma unroll
            for (int g = 0; g < 2; g++)
                #pragma unroll
                for (int c = 0; c < 4; c++)
                    acc[g][c] = __builtin_amdgcn_mfma_f32_32x32x16_bf16(ah[g], bh[c], acc[g][c], 0, 0, 0);
            #pragma unroll
            for (int g = 0; g < 2; g++)
                #pragma unroll
                for (int c = 0; c < 4; c++)
                    acc[g][c] = __builtin_amdgcn_mfma_f32_32x32x16_bf16(ah[g], bl[c], acc[g][c], 0, 0, 0);
            #pragma unroll
            for (int g = 0; g < 2; g++)
                #pragma unroll
                for (int c = 0; c < 4; c++)
                    acc[g][c] = __builtin_amdgcn_mfma_f32_32x32x16_bf16(al[g], bh[c], acc[g][c], 0, 0, 0);
        }
    }

    float dmin = 1e30f;
    const float* rowN = &smN[64 * wy];
    const float* colN = &smN[BTM + 128 * wx];
    #pragma unroll
    for (int g = 0; g < 2; g++)
        #pragma unroll
        for (int c = 0; c < 4; c++) {
            float cn = colN[32 * c + fp];
            #pragma unroll
            for (int r = 0; r < 16; r++) {
                int r32 = (r & 3) + 8 * (r >> 2) + 4 * fh;
                float d2 = rowN[32 * g + r32] + cn - 2.0f * acc[g][c][r];
                dmin = fminf(dmin, d2);
            }
        }

    #pragma unroll
    for (int off = 32; off > 0; off >>= 1) dmin = fminf(dmin, __shfl_down(dmin, off));
    if (lane == 0) wmin[wave] = dmin;
    __syncthreads();
    if (tid == 0)
        atomicMin(&minkey[zidx],
                  float_key(fminf(fminf(wmin[0], wmin[1]), fminf(wmin[2], wmin[3]))));
}

__global__ void finalize_kernel(const double* __restrict__ accum,
                                const unsigned* __restrict__ minkey,
                                float* __restrict__ out, int N, int M) {
    if (threadIdx.x == 0 && blockIdx.x == 0) {
        float Sp[3];
        #pragma unroll
        for (int z = 0; z < 3; z++) {
            float m = key_float(minkey[z]) * (-1.0f / 512.0f);
            double Sshift = accum[z] * exp(-(double)m);
            float r = (float)log(Sshift);        // correctly-rounded f32 log
            float lse = r + m;                   // fp32 add, as jax
            Sp[z] = (float)exp((double)lse);     // correctly-rounded f32 exp
        }
        float nf  = (float)N, mf = (float)M;
        float nn1 = (float)((double)N * (double)(N - 1));
        float mm1 = (float)((double)M * (double)(M - 1));
        float nm  = (float)((double)N * (double)M);
        float xx = (Sp[0] - nf) / nn1;
        float xy =  Sp[1]       / nm;
        float yy = (Sp[2] - mf) / mm1;
        out[0] = xx - 2.0f * xy + yy;
    }
}

extern "C" void kernel_launch(void* const* d_in, const int* in_sizes, int n_in,
                              void* d_out, int out_size, void* d_ws, size_t ws_size,
                              hipStream_t stream) {
    const float* X = (const float*)d_in[0];
    const float* Y = (const float*)d_in[1];
    const int N = in_sizes[0] / D;
    const int M = in_sizes[1] / D;
    const int gx = N / BTM, gy = M / BTN;        // 64 x 32

    double*   accum  = (double*)d_ws;
    unsigned* minkey = (unsigned*)((char*)d_ws + 32);
    float*    gmin   = (float*)((char*)d_ws + 48);
    float*    X2     = (float*)((char*)d_ws + 64);
    float*    Y2     = X2 + N;
    float*    bmin   = Y2 + M;
    size_t off = (64 + (size_t)(N + M) * 4 + (size_t)gx * gy * 4 + 255) & ~(size_t)255;
    size_t asz = (size_t)N * D * 2;
    uint4* Xh = (uint4*)((char*)d_ws + off);
    uint4* Yh = (uint4*)((char*)d_ws + off + asz);

    init_kernel<<<1, 64, 0, stream>>>(accum, minkey);

    row_norms_kernel<<<(N + M + 3) / 4, 256, 0, stream>>>(X, Y, X2, Y2, N, M);
    convert_h_kernel<<<dim3((N + 255) / 256, KSTEPS, 2), 256, 0, stream>>>(X, Y, Xh, Yh, N);

    diag_min_bits_kernel<<<N / 128 + M / 128, 256, 0, stream>>>(X, Y, X2, Y2, minkey, N / 128);

    dim3 grid(gx, gy, 3);
    pair_exp_sum_kernel<<<grid, 256, 0, stream>>>(Xh, Yh, X2, Y2, accum, bmin, N, M);

    xy_gmin_kernel<<<1, 256, 0, stream>>>(bmin, gmin, gx * gy);
    refine_min_kernel<<<dim3(gx, gy), 256, 0, stream>>>(X, Y, X2, Y2, bmin, gmin,
                                                        minkey, 1);

    finalize_kernel<<<1, 64, 0, stream>>>(accum, minkey, (float*)d_out, N, M);
}

// Round 12
// 311.058 us; speedup vs baseline: 1.8136x; 1.0441x over previous
//
#include <hip/hip_runtime.h>
#include <math.h>

// MMD, Gaussian kernel, bandwidth=512. X:[8192,512] Y:[8192,512] fp32.
// S_AB = sum_ij exp(-||a_i-b_j||^2/512); final combine emulates the
// reference's fp32 logsumexp->exp->combine path (see finalize_kernel).
//
// Architecture (validated R9-R11): fp16 single-product MFMA S-pass (S needs
// << 1 fp32 lse cell = 17 units of 9.1e6) + bit-exact reproduction of the
// R5 bf16-split 3-product d2 min for m (lse cell shifts with m at sub-ulp
// granularity -> m must be the exact winning bits; XX/YY via 32x32 diag
// self-tiles, XY via banded refine).
// Round-12: (1) pair kernel stages FOUR k-steps (32 KB) per LDS buffer ->
// one barrier per 128 CU-MFMAs (R11 at 64 still exposed the vmcnt(0) drain:
// 990->~600 cyc/interval-pair, MfmaUtil 34%). LDS 2x32KB keeps 2 blocks/CU.
// (2) XY refine at 1024 threads / 16 waves x 2 tiles (per-acc k-chain
// unchanged -> same bits, ~4x less serial latency).
// K-steps processed 0..31 sequentially, per-kstep MFMA order unchanged ->
// all sums/mins bit-identical to R11.

#define D      512
#define BTM    128
#define BTN    256
#define BK     16
#define KSTEPS (D / BK)

// 16B-unit offsets in the XY refine kernel's LDS (R5 layout [point*2+khalf])
#define AHI 0
#define ALO 256
#define BHI 512
#define BLO 1024

typedef _Float16 half8 __attribute__((ext_vector_type(8)));
typedef __attribute__((ext_vector_type(8)))  short  short8;   // 8 bf16
typedef __attribute__((ext_vector_type(16))) float  f32x16;   // 32x32 acc

union U4H8 { uint4 u; half8 h; };
union U4S8 { uint4 u; short8 s; };

__device__ __forceinline__ unsigned short bf16_rne(float x) {
    unsigned u = __float_as_uint(x);
    return (unsigned short)((u + 0x7fffu + ((u >> 16) & 1u)) >> 16);
}
__device__ __forceinline__ float bf16_f32(unsigned short b) {
    return __uint_as_float(((unsigned)b) << 16);
}
__device__ __forceinline__ void split8(const float v[8], uint4& hi, uint4& lo) {
    unsigned h[8], l[8];
    #pragma unroll
    for (int j = 0; j < 8; j++) {
        unsigned short bh = bf16_rne(v[j]);
        float r = v[j] - bf16_f32(bh);          // exact (Sterbenz)
        unsigned short bl = bf16_rne(r);
        h[j] = bh; l[j] = bl;
    }
    hi.x = h[0] | (h[1] << 16); hi.y = h[2] | (h[3] << 16);
    hi.z = h[4] | (h[5] << 16); hi.w = h[6] | (h[7] << 16);
    lo.x = l[0] | (l[1] << 16); lo.y = l[2] | (l[3] << 16);
    lo.z = l[4] | (l[5] << 16); lo.w = l[6] | (l[7] << 16);
}

// async global->LDS, 16B per lane
__device__ __forceinline__ void lds16(const uint4* g, uint4* l) {
    __builtin_amdgcn_global_load_lds(
        (const __attribute__((address_space(1))) void*)g,
        (__attribute__((address_space(3))) void*)(unsigned int)(uintptr_t)(void*)l,
        16, 0, 0);
}

__global__ void init_kernel(double* accum, unsigned* minkey) {
    if (threadIdx.x < 3) accum[threadIdx.x] = 0.0;
    if (threadIdx.x < 4) minkey[threadIdx.x] = 0xFFFFFFFFu;
}

// fp16 convert: src[npts][512] fp32 -> [kstep][p>>5][khalf][p&31] 16B units
__global__ __launch_bounds__(256)
void convert_h_kernel(const float* __restrict__ X, const float* __restrict__ Y,
                      uint4* __restrict__ Xh, uint4* __restrict__ Yh, int npts) {
    const float* src = blockIdx.z ? Y : X;
    uint4*       dst = blockIdx.z ? Yh : Xh;
    const int ks = blockIdx.y;
    const int p  = blockIdx.x * 256 + threadIdx.x;
    if (p >= npts) return;
    const float* s = src + (size_t)p * D + ks * BK;
    float v[16];
    *(float4*)&v[0]  = *(const float4*)(s);
    *(float4*)&v[4]  = *(const float4*)(s + 4);
    *(float4*)&v[8]  = *(const float4*)(s + 8);
    *(float4*)&v[12] = *(const float4*)(s + 12);
    U4H8 a, b;
    #pragma unroll
    for (int j = 0; j < 8; j++) { a.h[j] = (_Float16)v[j]; b.h[j] = (_Float16)v[8 + j]; }
    size_t u = (size_t)ks * npts * 2 + (size_t)(p >> 5) * 64 + (p & 31);
    dst[u] = a.u; dst[u + 32] = b.u;
}

__global__ __launch_bounds__(256)
void row_norms_kernel(const float* __restrict__ X, const float* __restrict__ Y,
                      float* __restrict__ X2, float* __restrict__ Y2, int N, int M) {
    const int wave = threadIdx.x >> 6;
    const int lane = threadIdx.x & 63;
    const int row  = blockIdx.x * 4 + wave;
    const float* src; float* dst; int r;
    if (row < N)          { src = X; dst = X2; r = row; }
    else if (row < N + M) { src = Y; dst = Y2; r = row - N; }
    else return;
    const float* p = src + (size_t)r * D;
    float s = 0.f;
    #pragma unroll
    for (int c = 0; c < D; c += 64) {
        float v = p[c + lane];
        s = fmaf(v, v, s);
    }
    #pragma unroll
    for (int off = 32; off > 0; off >>= 1) s += __shfl_down(s, off);
    if (lane == 0) dst[r] = s;
}

__device__ inline unsigned float_key(float f) {
    unsigned u = __float_as_uint(f);
    return (u & 0x80000000u) ? ~u : (u | 0x80000000u);
}
__device__ inline float key_float(unsigned k) {
    return __uint_as_float((k & 0x80000000u) ? (k ^ 0x80000000u) : ~k);
}

// ---- XX/YY m: R5-bit-exact diag d2 via 32x32 self-tiles (fused X+Y) ------
__global__ __launch_bounds__(256)
void diag_min_bits_kernel(const float* __restrict__ X, const float* __restrict__ Y,
                          const float* __restrict__ X2, const float* __restrict__ Y2,
                          unsigned* __restrict__ minkey, int ngx) {
    int b = blockIdx.x;
    const float *src, *n2; int zidx;
    if (b < ngx) { src = X; n2 = X2; zidx = 0; }
    else         { src = Y; n2 = Y2; zidx = 2; b -= ngx; }

    const int tid  = threadIdx.x;
    const int wave = tid >> 6, lane = tid & 63;
    const int grp  = b * 4 + wave;                // 32-point group id
    const int fp   = lane & 31, fh = lane >> 5;
    const int pt   = grp * 32 + fp;
    const float* s = src + (size_t)pt * D + fh * 8;

    f32x16 acc;
    #pragma unroll
    for (int i = 0; i < 16; i++) acc[i] = 0.f;

    for (int ks = 0; ks < KSTEPS; ks++) {
        float v[8];
        *(float4*)&v[0] = *(const float4*)(s + ks * BK);
        *(float4*)&v[4] = *(const float4*)(s + ks * BK + 4);
        U4S8 hi, lo;
        split8(v, hi.u, lo.u);
        short8 ah = hi.s, al = lo.s;
        // R5 order: hh, h*lB, lA*h (A-frag == B-frag here)
        acc = __builtin_amdgcn_mfma_f32_32x32x16_bf16(ah, ah, acc, 0, 0, 0);
        acc = __builtin_amdgcn_mfma_f32_32x32x16_bf16(ah, al, acc, 0, 0, 0);
        acc = __builtin_amdgcn_mfma_f32_32x32x16_bf16(al, ah, acc, 0, 0, 0);
    }

    float dmin = 1e30f;
    if (fh == ((fp >> 2) & 1)) {
        int r = (fp & 3) + 4 * (fp >> 3);
        float av = acc[r];
        float rn = n2[pt];
        float cn = rn;
        float d2 = rn + cn - 2.0f * av;           // exact: contraction-safe
        dmin = d2;
    }
    #pragma unroll
    for (int off = 32; off > 0; off >>= 1) dmin = fminf(dmin, __shfl_down(dmin, off));
    __shared__ float wm[4];
    __shared__ int   wz[4];
    if (lane == 0) { wm[wave] = dmin; wz[wave] = zidx; }
    __syncthreads();
    if (tid == 0)
        atomicMin(&minkey[wz[0]],
                  float_key(fminf(fminf(wm[0], wm[1]), fminf(wm[2], wm[3]))));
}

// ---------- fp16 S-pass: grid (64,32,3): z=0 XX (sym), 1 XY, 2 YY ----------
__global__ __launch_bounds__(256, 2)
void pair_exp_sum_kernel(const uint4* __restrict__ Xh, const uint4* __restrict__ Yh,
                         const float* __restrict__ X2, const float* __restrict__ Y2,
                         double* __restrict__ accum, float* __restrict__ bmin,
                         int N, int M) {
    const int z = blockIdx.z;
    const uint4 *Ah, *Bh; const float *An, *Bn; bool sym; int na, nb;
    if (z == 0)      { Ah = Xh; Bh = Xh; An = X2; Bn = X2; sym = true;  na = N; nb = N; }
    else if (z == 1) { Ah = Xh; Bh = Yh; An = X2; Bn = Y2; sym = false; na = N; nb = M; }
    else             { Ah = Yh; Bh = Yh; An = Y2; Bn = Y2; sym = true;  na = M; nb = M; }
    const int bi = blockIdx.x, bj = blockIdx.y;
    if (sym && (2 * bj + 1) < bi) return;        // both 128-col halves below diag

    __shared__ uint4  smem[2][2048];             // 2 bufs x 32 KB (4 ksteps each)
    __shared__ float  smN[BTM + BTN];
    __shared__ double wsum[4];
    __shared__ float  wmin[4];

    const int tid  = threadIdx.x;
    const int wave = tid >> 6, lane = tid & 63;
    const int wy = wave >> 1, wx = wave & 1;     // 2x2 waves, each 64x128
    const int row0 = bi * BTM, col0 = bj * BTN;

    if (tid < BTM) smN[tid] = An[row0 + tid];
    smN[BTM + tid] = Bn[col0 + tid];

    const int wl = wave * 64 + lane;
    const size_t strideA = (size_t)na * 2;       // 16B units per kstep
    const size_t strideB = (size_t)nb * 2;
    const uint4* gB0 = Bh + (size_t)(col0 >> 5) * 64 + wl;
    const uint4* gB1 = gB0 + 256;
    const half8* gA0 = (const half8*)Ah + ((size_t)(row0 >> 5) + 2 * wy) * 64 + lane;
    const half8* gA1 = gA0 + 64;

    f32x16 acc[2][4];
    #pragma unroll
    for (int g = 0; g < 2; g++)
        #pragma unroll
        for (int c = 0; c < 4; c++)
            #pragma unroll
            for (int i = 0; i < 16; i++) acc[g][c][i] = 0.f;

    // stage FOUR k-steps (32 KB) into one buffer; kstep j at unit j*512
    auto stage4 = [&](int buf, int ks) {
        #pragma unroll
        for (int j = 0; j < 4; j++) {
            lds16(gB0 + (size_t)(ks + j) * strideB, &smem[buf][j * 512 + wl]);
            lds16(gB1 + (size_t)(ks + j) * strideB, &smem[buf][j * 512 + 256 + wl]);
        }
    };
    half8 Af[8][2];                              // [slot][g]; 4 slots per buffer
    auto loadA4 = [&](int ks, int s) {
        #pragma unroll
        for (int j = 0; j < 4; j++) {
            Af[s + j][0] = gA0[(size_t)(ks + j) * strideA];
            Af[s + j][1] = gA1[(size_t)(ks + j) * strideA];
        }
    };
    auto computeK = [&](const uint4* base, int slot) {   // one kstep
        const half8* p = (const half8*)base;
        half8 bh[4];
        #pragma unroll
        for (int c = 0; c < 4; c++) bh[c] = p[(4 * wx + c) * 64 + lane];
        #pragma unroll
        for (int g = 0; g < 2; g++)
            #pragma unroll
            for (int c = 0; c < 4; c++)
                acc[g][c] = __builtin_amdgcn_mfma_f32_32x32x16_f16(Af[slot][g], bh[c], acc[g][c], 0, 0, 0);
    };

    stage4(0, 0);
    loadA4(0, 0);
    __syncthreads();

    #pragma unroll
    for (int it = 1; it < KSTEPS / 4; it++) {    // 7 intervals
        stage4(it & 1, 4 * it);                  // prefetch next quad
        loadA4(4 * it, (it & 1) * 4);
        const int pb = (it - 1) & 1, ps = pb * 4;
        computeK(&smem[pb][0],    ps + 0);       // ksteps 4(it-1)..4(it-1)+3
        computeK(&smem[pb][512],  ps + 1);
        computeK(&smem[pb][1024], ps + 2);
        computeK(&smem[pb][1536], ps + 3);
        __syncthreads();                         // drains DMAs issued this interval
    }
    computeK(&smem[1][0],    4);                 // ksteps 28..31
    computeK(&smem[1][512],  5);
    computeK(&smem[1][1024], 6);
    computeK(&smem[1][1536], 7);

    float wgt = 1.f;
    if (sym) {
        int cblk = 2 * bj + wx;
        wgt = (cblk > bi) ? 2.f : (cblk == bi ? 1.f : 0.f);
    }

    // C/D layout (m74/m101): col=lane&31, row=(reg&3)+8*(reg>>2)+4*(lane>>5)
    const int fp = lane & 31, fh = lane >> 5;
    double s = 0.0;
    float dmin = 1e30f;
    if (wgt != 0.f) {
        const float* rowN = &smN[64 * wy];
        const float* colN = &smN[BTM + 128 * wx];
        const float kC = -0.0028177637517362567f;   // -log2(e)/512
        #pragma unroll
        for (int g = 0; g < 2; g++)
            #pragma unroll
            for (int c = 0; c < 4; c++) {
                float cn = colN[32 * c + fp];
                float rs = 0.f;
                #pragma unroll
                for (int r = 0; r < 16; r++) {
                    int r32 = (r & 3) + 8 * (r >> 2) + 4 * fh;
                    float d2 = rowN[32 * g + r32] + cn - 2.0f * acc[g][c][r];
                    dmin = fminf(dmin, d2);
                    rs += exp2f(d2 * kC);            // v_exp_f32; args in [-4.2,0]
                }
                s += (double)rs;
            }
        s *= (double)wgt;
    }

    #pragma unroll
    for (int off = 32; off > 0; off >>= 1) {
        s += __shfl_down(s, off);
        dmin = fminf(dmin, __shfl_down(dmin, off));
    }
    if (lane == 0) { wsum[wave] = s; wmin[wave] = dmin; }
    __syncthreads();
    if (tid == 0) {
        atomicAdd(&accum[z], wsum[0] + wsum[1] + wsum[2] + wsum[3]);
        if (z == 1)                              // noisy (+-~0.05) block min
            bmin[bi * gridDim.y + bj] = fminf(fminf(wmin[0], wmin[1]),
                                              fminf(wmin[2], wmin[3]));
    }
}

__global__ __launch_bounds__(256)
void xy_gmin_kernel(const float* __restrict__ bmin, float* __restrict__ gmin, int nblk) {
    float m = 1e30f;
    for (int i = threadIdx.x; i < nblk; i += 256) m = fminf(m, bmin[i]);
    #pragma unroll
    for (int off = 32; off > 0; off >>= 1) m = fminf(m, __shfl_down(m, off));
    __shared__ float wm[4];
    if ((threadIdx.x & 63) == 0) wm[threadIdx.x >> 6] = m;
    __syncthreads();
    if (threadIdx.x == 0) gmin[0] = fminf(fminf(wm[0], wm[1]), fminf(wm[2], wm[3]));
}

// ---------- XY refine: R5-bit-exact bf16-split 3-product d2 min -----------
// 1024 threads / 16 waves; wave w owns row-group gy=w&3 (32 rows) and col
// groups 2*(w>>2), 2*(w>>2)+1. Per-accumulator k-chain (hh,hl,lh per kstep,
// ks 0..31) identical to R5 -> same d2 bits; ~4x less serial latency.
__global__ __launch_bounds__(1024)
void refine_min_kernel(const float* __restrict__ A, const float* __restrict__ B,
                       const float* __restrict__ An, const float* __restrict__ Bn,
                       const float* __restrict__ bmin, const float* __restrict__ gmin,
                       unsigned* __restrict__ minkey, int zidx) {
    const int bi = blockIdx.x;
    const int bj = blockIdx.y;
    if (!(bmin[bi * gridDim.y + bj] < gmin[0] + 0.5f)) return;
    const int row0 = bi * BTM, col0 = bj * BTN;

    __shared__ uint4 smem[1536];                 // Ahi|Alo|Bhi|Blo (R5 layout)
    __shared__ float smN[BTM + BTN];
    __shared__ float wmin[16];

    const int tid  = threadIdx.x;
    const int wave = tid >> 6, lane = tid & 63;
    const int gy = wave & 3, cg0 = 2 * (wave >> 2);
    if (tid < BTM) smN[tid] = An[row0 + tid];
    if (tid < BTN) smN[BTM + tid] = Bn[col0 + tid];

    const int fp = lane & 31, fh = lane >> 5;
    const int au = (32 * gy + fp) * 2 + fh;
    int bu[2];
    #pragma unroll
    for (int c = 0; c < 2; c++) bu[c] = (32 * (cg0 + c) + fp) * 2 + fh;

    f32x16 acc[2];
    #pragma unroll
    for (int c = 0; c < 2; c++)
        #pragma unroll
        for (int i = 0; i < 16; i++) acc[c][i] = 0.f;

    for (int ks = 0; ks < KSTEPS; ks++) {
        __syncthreads();                         // prev-step LDS reads done
        if (tid < 256) {                         // A: unit tid
            const float* s = A + (size_t)(row0 + (tid >> 1)) * D + ks * BK + (tid & 1) * 8;
            float v[8];
            *(float4*)&v[0] = *(const float4*)s;
            *(float4*)&v[4] = *(const float4*)(s + 4);
            uint4 hi, lo; split8(v, hi, lo);
            smem[AHI + tid] = hi; smem[ALO + tid] = lo;
        } else if (tid < 768) {                  // B: unit tid-256
            int u = tid - 256;
            const float* s = B + (size_t)(col0 + (u >> 1)) * D + ks * BK + (u & 1) * 8;
            float v[8];
            *(float4*)&v[0] = *(const float4*)s;
            *(float4*)&v[4] = *(const float4*)(s + 4);
            uint4 hi, lo; split8(v, hi, lo);
            smem[BHI + u] = hi; smem[BLO + u] = lo;
        }
        __syncthreads();
        {   // per-acc chain: hh, hl, lh (matches R5 acc[g][c] chain order)
            const short8* p = (const short8*)&smem[0];
            short8 ah = p[AHI + au], al = p[ALO + au];
            short8 bh[2], bl[2];
            #pragma unroll
            for (int c = 0; c < 2; c++) { bh[c] = p[BHI + bu[c]]; bl[c] = p[BLO + bu[c]]; }
            #pragma unroll
            for (int c = 0; c < 2; c++)
                acc[c] = __builtin_amdgcn_mfma_f32_32x32x16_bf16(ah, bh[c], acc[c], 0, 0, 0);
            #pragma unroll
            for (int c = 0; c < 2; c++)
                acc[c] = __builtin_amdgcn_mfma_f32_32x32x16_bf16(ah, bl[c], acc[c], 0, 0, 0);
            #pragma unroll
            for (int c = 0; c < 2; c++)
                acc[c] = __builtin_amdgcn_mfma_f32_32x32x16_bf16(al, bh[c], acc[c], 0, 0, 0);
        }
    }

    float dmin = 1e30f;
    const float* rowN = &smN[32 * gy];
    #pragma unroll
    for (int c = 0; c < 2; c++) {
        float cn = smN[BTM + 32 * (cg0 + c) + fp];
        #pragma unroll
        for (int r = 0; r < 16; r++) {
            int r32 = (r & 3) + 8 * (r >> 2) + 4 * fh;
            float d2 = rowN[r32] + cn - 2.0f * acc[c][r];
            dmin = fminf(dmin, d2);
        }
    }

    #pragma unroll
    for (int off = 32; off > 0; off >>= 1) dmin = fminf(dmin, __shfl_down(dmin, off));
    if (lane == 0) wmin[wave] = dmin;
    __syncthreads();
    if (tid == 0) {
        float m = wmin[0];
        #pragma unroll
        for (int w = 1; w < 16; w++) m = fminf(m, wmin[w]);
        atomicMin(&minkey[zidx], float_key(m));
    }
}

__global__ void finalize_kernel(const double* __restrict__ accum,
                                const unsigned* __restrict__ minkey,
                                float* __restrict__ out, int N, int M) {
    if (threadIdx.x == 0 && blockIdx.x == 0) {
        float Sp[3];
        #pragma unroll
        for (int z = 0; z < 3; z++) {
            float m = key_float(minkey[z]) * (-1.0f / 512.0f);
            double Sshift = accum[z] * exp(-(double)m);
            float r = (float)log(Sshift);        // correctly-rounded f32 log
            float lse = r + m;                   // fp32 add, as jax
            Sp[z] = (float)exp((double)lse);     // correctly-rounded f32 exp
        }
        float nf  = (float)N, mf = (float)M;
        float nn1 = (float)((double)N * (double)(N - 1));
        float mm1 = (float)((double)M * (double)(M - 1));
        float nm  = (float)((double)N * (double)M);
        float xx = (Sp[0] - nf) / nn1;
        float xy =  Sp[1]       / nm;
        float yy = (Sp[2] - mf) / mm1;
        out[0] = xx - 2.0f * xy + yy;
    }
}

extern "C" void kernel_launch(void* const* d_in, const int* in_sizes, int n_in,
                              void* d_out, int out_size, void* d_ws, size_t ws_size,
                              hipStream_t stream) {
    const float* X = (const float*)d_in[0];
    const float* Y = (const float*)d_in[1];
    const int N = in_sizes[0] / D;
    const int M = in_sizes[1] / D;
    const int gx = N / BTM, gy = M / BTN;        // 64 x 32

    double*   accum  = (double*)d_ws;
    unsigned* minkey = (unsigned*)((char*)d_ws + 32);
    float*    gmin   = (float*)((char*)d_ws + 48);
    float*    X2     = (float*)((char*)d_ws + 64);
    float*    Y2     = X2 + N;
    float*    bmin   = Y2 + M;
    size_t off = (64 + (size_t)(N + M) * 4 + (size_t)gx * gy * 4 + 255) & ~(size_t)255;
    size_t asz = (size_t)N * D * 2;
    uint4* Xh = (uint4*)((char*)d_ws + off);
    uint4* Yh = (uint4*)((char*)d_ws + off + asz);

    init_kernel<<<1, 64, 0, stream>>>(accum, minkey);

    row_norms_kernel<<<(N + M + 3) / 4, 256, 0, stream>>>(X, Y, X2, Y2, N, M);
    convert_h_kernel<<<dim3((N + 255) / 256, KSTEPS, 2), 256, 0, stream>>>(X, Y, Xh, Yh, N);

    diag_min_bits_kernel<<<N / 128 + M / 128, 256, 0, stream>>>(X, Y, X2, Y2, minkey, N / 128);

    dim3 grid(gx, gy, 3);
    pair_exp_sum_kernel<<<grid, 256, 0, stream>>>(Xh, Yh, X2, Y2, accum, bmin, N, M);

    xy_gmin_kernel<<<1, 256, 0, stream>>>(bmin, gmin, gx * gy);
    refine_min_kernel<<<dim3(gx, gy), 1024, 0, stream>>>(X, Y, X2, Y2, bmin, gmin,
                                                         minkey, 1);

    finalize_kernel<<<1, 64, 0, stream>>>(accum, minkey, (float*)d_out, N, M);
}